// Round 2
// baseline (866.175 us; speedup 1.0000x reference)
//
#include <hip/hip_runtime.h>
#include <stdint.h>

#define L48   48
#define NLOC  2304      // 48*48
#define C3CH  256
#define KDIM  2304      // 256*9
#define BATCH 4
#define PADLOC 2400     // 50 rows * 48

typedef _Float16 half8 __attribute__((ext_vector_type(8)));
typedef float    floatx4 __attribute__((ext_vector_type(4)));
typedef unsigned short ushort8v __attribute__((ext_vector_type(8)));

union H16 { _Float16 f; unsigned short u; };

// ---------------- norms: one wave per patch location (unchanged) ----------------
__global__ __launch_bounds__(256) void norm_kernel(const float* __restrict__ img,
                                                   float* __restrict__ inv_norm)
{
    int wid  = (blockIdx.x * 256 + threadIdx.x) >> 6;
    int lane = threadIdx.x & 63;
    if (wid >= BATCH * NLOC) return;
    int b = wid / NLOC;
    int m = wid - b * NLOC;
    int y = m / L48, x = m - y * L48;
    const float* base = img + (size_t)b * C3CH * NLOC;
    float acc = 0.f;
    for (int e = lane; e < KDIM; e += 64) {
        int c = e / 9;
        int r = e - c * 9;
        int yy = y + r / 3 - 1;
        int xx = x + (r % 3) - 1;
        float v = 0.f;
        if ((unsigned)yy < 48u && (unsigned)xx < 48u)
            v = base[c * NLOC + yy * L48 + xx];
        acc += v * v;
    }
    #pragma unroll
    for (int off = 32; off >= 1; off >>= 1)
        acc += __shfl_xor(acc, off, 64);
    if (lane == 0) {
        float n = fmaxf(sqrtf(acc), 1e-12f);
        inv_norm[wid] = 1.f / n;
    }
}

// ---------------- prep: fp32 image -> K-major granule split-fp16 (unchanged) ----------------
__global__ __launch_bounds__(256) void prep_kernel(const float* __restrict__ img,
                                                   unsigned short* __restrict__ out_hi,
                                                   unsigned short* __restrict__ out_lo)
{
    __shared__ unsigned short hi[256 * 50];
    __shared__ unsigned short lo[256 * 50];
    int bid = blockIdx.x;
    int oxIdx = bid / 200;
    int rem   = bid % 200;
    int b     = rem / 50;
    int yy    = rem % 50;
    int kj = oxIdx - 1;
    int y  = yy - 1;
    int t = threadIdx.x;
    bool yok = (unsigned)y < 48u;
    const float* ibase = img + (size_t)b * C3CH * NLOC;
    for (int flat = t; flat < 256 * 48; flat += 256) {
        int c = flat / 48;
        int x = flat - c * 48;
        int xs = x + kj;
        float v = 0.f;
        if (yok && (unsigned)xs < 48u)
            v = ibase[c * NLOC + y * L48 + xs];
        H16 h, l;
        h.f = (_Float16)v;
        float rvv = (v - (float)h.f) * 2048.0f;
        l.f = (_Float16)rvv;
        hi[c * 50 + x] = h.u;
        lo[c * 50 + x] = l.u;
    }
    __syncthreads();
    size_t plane = (size_t)(oxIdx * 4 + b);
    for (int flat = t; flat < 32 * 48; flat += 256) {
        int G = flat / 48;
        int x = flat - G * 48;
        ushort8v vh, vl;
        #pragma unroll
        for (int j = 0; j < 8; ++j) {
            vh[j] = hi[(G * 8 + j) * 50 + x];
            vl[j] = lo[(G * 8 + j) * 50 + x];
        }
        size_t o8 = ((plane * 32 + G) * PADLOC + (size_t)yy * 48 + x) * 8;
        *(ushort8v*)(out_hi + o8) = vh;
        *(ushort8v*)(out_lo + o8) = vl;
    }
}

// ---------------- search: fp16 hi/lo split MFMA GEMM, counted-vmcnt pipeline ----------------
__device__ __forceinline__ void stage_arr(const unsigned short* __restrict__ gbase,
                                          int loc0,
                                          unsigned short* lbase,
                                          int wv, int lane)
{
    #pragma unroll
    for (int j = 0; j < 2; ++j) {
        int bg = (j * 4 + wv) * 64;          // base granule in [0,512)
        int q  = bg >> 7;
        int r0 = bg & 127;
        const unsigned short* gp = gbase + ((size_t)q * PADLOC + loc0 + r0 + lane) * 8;
        unsigned short* lp = lbase + (size_t)(bg + lane) * 8;
        __builtin_amdgcn_global_load_lds((const __attribute__((address_space(1))) void*)gp,
                                         (__attribute__((address_space(3))) void*)lp,
                                         16, 0, 0);
    }
}

__global__ __launch_bounds__(256, 2) void search_mfma(const unsigned short* __restrict__ At_hi,
                                                      const unsigned short* __restrict__ At_lo,
                                                      const unsigned short* __restrict__ Bt_hi,
                                                      const unsigned short* __restrict__ Bt_lo,
                                                      const float* __restrict__ nr_inv,
                                                      unsigned long long* __restrict__ packed)
{
    // 2 buffers x 4 arrays x 4096 ushorts (8KB) = 65536 B
    __shared__ __align__(16) unsigned short lds[2 * 4 * 4096];

    const int tid = threadIdx.x;
    const int b  = blockIdx.z;
    const int l0 = blockIdx.y * 128;
    const int m0 = blockIdx.x * 128;

    const int lane = tid & 63;
    const int wv = tid >> 6;          // wave id 0..3
    const int wr = tid >> 7;          // wave row 0..1
    const int wc = (tid >> 6) & 1;    // wave col 0..1
    const int mrow = lane & 15;
    const int q = lane >> 4;          // k-granule 0..3

    floatx4 acc1[4][4];
    floatx4 acc2[4][4];
    #pragma unroll
    for (int i = 0; i < 4; ++i)
        #pragma unroll
        for (int j = 0; j < 4; ++j) { acc1[i][j] = (floatx4)0.f; acc2[i][j] = (floatx4)0.f; }

    auto issue = [&](int it, int sel) {
        int o  = it >> 3;
        int cc = it & 7;
        int od3 = o / 3;
        int ki  = od3 - 1;
        int ox  = o - od3 * 3;
        int plane = ox * 4 + b;
        int locA = l0 + 48 * (1 + ki);
        int locB = m0 + 48 * (1 + ki);
        size_t gb = (size_t)(plane * 32 + cc * 4) * (PADLOC * 8);
        unsigned short* L = (unsigned short*)lds + sel * 16384;
        stage_arr(At_hi + gb, locA, L,         wv, lane);
        stage_arr(At_lo + gb, locA, L + 4096,  wv, lane);
        stage_arr(Bt_hi + gb, locB, L + 8192,  wv, lane);
        stage_arr(Bt_lo + gb, locB, L + 12288, wv, lane);
    };

    issue(0, 0);   // 8 loads/wave in flight for buf0

    for (int it = 0; it < 72; ++it) {
        const int sel = it & 1;
        if (it + 1 < 72) {
            issue(it + 1, sel ^ 1);                       // 8 more in flight (buf sel^1)
            // wait for the 8 OLDEST (this iter's buf[sel]); keep the 8 newest in flight
            asm volatile("s_waitcnt vmcnt(8)" ::: "memory");
        } else {
            asm volatile("s_waitcnt vmcnt(0)" ::: "memory");
        }
        __builtin_amdgcn_s_barrier();
        asm volatile("" ::: "memory");   // keep LDS reads below the barrier

        const _Float16* L  = (const _Float16*)((unsigned short*)lds + sel * 16384);
        const _Float16* Ah = L;
        const _Float16* Al = L + 4096;
        const _Float16* Bh = L + 8192;
        const _Float16* Bl = L + 12288;

        half8 ahf[4], alf[4];
        #pragma unroll
        for (int fi = 0; fi < 4; ++fi) {
            int g = q * 128 + wr * 64 + fi * 16 + mrow;
            ahf[fi] = *(const half8*)(Ah + g * 8);
            alf[fi] = *(const half8*)(Al + g * 8);
        }
        #pragma unroll
        for (int fj = 0; fj < 4; ++fj) {
            int g = q * 128 + wc * 64 + fj * 16 + mrow;
            half8 bhf = *(const half8*)(Bh + g * 8);
            half8 blf = *(const half8*)(Bl + g * 8);
            __builtin_amdgcn_s_setprio(1);
            #pragma unroll
            for (int fi = 0; fi < 4; ++fi) {
                acc1[fi][fj] = __builtin_amdgcn_mfma_f32_16x16x32_f16(ahf[fi], bhf, acc1[fi][fj], 0, 0, 0);
                acc2[fi][fj] = __builtin_amdgcn_mfma_f32_16x16x32_f16(ahf[fi], blf, acc2[fi][fj], 0, 0, 0);
                acc2[fi][fj] = __builtin_amdgcn_mfma_f32_16x16x32_f16(alf[fi], bhf, acc2[fi][fj], 0, 0, 0);
            }
            __builtin_amdgcn_s_setprio(0);
        }
        // no end-of-iter barrier: next iter's top barrier orders read-before-overwrite
    }

    __syncthreads();   // all waves done reading LDS before epilogue reuses it

    // ---- epilogue: row-normalize, per-column argmax over l within block ----
    float* redv = (float*)lds;               // [8][128]
    int*   redi = (int*)(redv + 8 * 128);    // [8][128]

    const float inv2048 = 1.0f / 2048.0f;
    float bestv[4];
    int   besti[4];
    #pragma unroll
    for (int fj = 0; fj < 4; ++fj) { bestv[fj] = -1e30f; besti[fj] = 0; }

    #pragma unroll
    for (int fi = 0; fi < 4; ++fi) {
        int rowbase = l0 + wr * 64 + fi * 16 + (lane >> 4) * 4;
        #pragma unroll
        for (int r = 0; r < 4; ++r) {
            float rinv = nr_inv[b * NLOC + rowbase + r];
            #pragma unroll
            for (int fj = 0; fj < 4; ++fj) {
                float v = (acc1[fi][fj][r] + acc2[fi][fj][r] * inv2048) * rinv;
                if (v > bestv[fj]) { bestv[fj] = v; besti[fj] = rowbase + r; }
            }
        }
    }

    int cand = wr * 4 + (lane >> 4);   // 0..7
    #pragma unroll
    for (int fj = 0; fj < 4; ++fj) {
        int col = wc * 64 + fj * 16 + mrow;
        redv[cand * 128 + col] = bestv[fj];
        redi[cand * 128 + col] = besti[fj];
    }
    __syncthreads();
    if (tid < 128) {
        float best = redv[tid];
        int   bi   = redi[tid];
        #pragma unroll
        for (int c = 1; c < 8; ++c) {
            float v  = redv[c * 128 + tid];
            int   i2 = redi[c * 128 + tid];
            if (v > best || (v == best && i2 < bi)) { best = v; bi = i2; }
        }
        unsigned int sv = __float_as_uint(best);
        sv = (sv & 0x80000000u) ? ~sv : (sv | 0x80000000u);
        unsigned long long p = ((unsigned long long)sv << 32)
                             | (unsigned long long)(0xFFFFFFFFu - (unsigned)bi);
        atomicMax(packed + b * NLOC + m0 + tid, p);
    }
}

// ---------------- finalize: unpack S and argmax (unchanged) ----------------
__global__ __launch_bounds__(256) void finalize_kernel(const unsigned long long* __restrict__ packed,
                                                       const float* __restrict__ nl_inv,
                                                       float* __restrict__ S,
                                                       int* __restrict__ Rarg)
{
    int i = blockIdx.x * 256 + threadIdx.x;
    if (i >= BATCH * NLOC) return;
    unsigned long long p = packed[i];
    unsigned int sv   = (unsigned int)(p >> 32);
    unsigned int bits = (sv & 0x80000000u) ? (sv & 0x7FFFFFFFu) : ~sv;
    float val = __uint_as_float(bits);
    int   idx = (int)(0xFFFFFFFFu - (unsigned int)(p & 0xFFFFFFFFu));
    S[i]    = val * nl_inv[i];
    Rarg[i] = idx;
}

// ------------- transfer: fused gather + fold, 8 channels per thread -------------
// Index math ((py,px) bounds, Rarg load, q magic-div decode) amortized over CHUNK channels.
template<int C, int H, int K, int S, int P, int CHUNK>
__global__ __launch_bounds__(256) void transfer_kernel(const float* __restrict__ ref,
                                                       const int* __restrict__ Rarg,
                                                       float* __restrict__ out)
{
    const int NG = C / CHUNK;
    int idx = blockIdx.x * 256 + threadIdx.x;
    if (idx >= BATCH * NG * H * H) return;
    int x = idx % H;
    int y = (idx / H) % H;
    int g = (idx / (H * H)) % NG;
    int b = idx / (H * H * NG);
    int c0 = g * CHUNK;
    int Y = y + P, X = x + P;
    int ylo = Y - K + 1; ylo = (ylo > 0) ? (ylo + S - 1) / S : 0;
    int yhi = Y / S; if (yhi > 47) yhi = 47;
    int xlo = X - K + 1; xlo = (xlo > 0) ? (xlo + S - 1) / S : 0;
    int xhi = X / S; if (xhi > 47) xhi = 47;
    const float* rbase = ref + ((size_t)b * C + c0) * H * H;
    const int*   abase = Rarg + b * NLOC;
    float acc[CHUNK];
    #pragma unroll
    for (int cc = 0; cc < CHUNK; ++cc) acc[cc] = 0.f;
    for (int py = ylo; py <= yhi; ++py) {
        int ki = Y - py * S;
        for (int px = xlo; px <= xhi; ++px) {
            int kj = X - px * S;
            int qv = abase[py * L48 + px];
            int qy = qv / L48, qx = qv - qy * L48;
            int row = qy * S + ki - P;
            int col = qx * S + kj - P;
            if ((unsigned)row < (unsigned)H && (unsigned)col < (unsigned)H) {
                const float* p = rbase + (size_t)row * H + col;
                #pragma unroll
                for (int cc = 0; cc < CHUNK; ++cc)
                    acc[cc] += p[(size_t)cc * H * H];
            }
        }
    }
    size_t obase = ((size_t)b * C + c0) * H * H + (size_t)y * H + x;
    #pragma unroll
    for (int cc = 0; cc < CHUNK; ++cc)
        out[obase + (size_t)cc * H * H] = acc[cc] * (1.f / 9.f);
}

extern "C" void kernel_launch(void* const* d_in, const int* in_sizes, int n_in,
                              void* d_out, int out_size, void* d_ws, size_t ws_size,
                              hipStream_t stream)
{
    const float* lrsr  = (const float*)d_in[0];
    const float* refsr = (const float*)d_in[1];
    const float* ref1  = (const float*)d_in[2];
    const float* ref2  = (const float*)d_in[3];
    const float* ref3  = (const float*)d_in[4];

    float* S_out  = (float*)d_out;                   // 9216
    float* T3_out = S_out  + BATCH * NLOC;           // 2359296
    float* T2_out = T3_out + BATCH * 256 * 48 * 48;  // 4718592
    float* T1_out = T2_out + BATCH * 128 * 96 * 96;  // 9437184

    char* ws = (char*)d_ws;
    unsigned long long* packed = (unsigned long long*)ws;         // 73728 B
    float* nr_inv = (float*)(ws + 73728);                         // 36864 B
    float* nl_inv = (float*)(ws + 110592);                        // 36864 B
    int*   Rarg   = (int*)(ws + 147456);                          // 36864 B
    const size_t TSZ = (size_t)3 * BATCH * PADLOC * 256;          // 7372800 elements
    unsigned short* A_hi = (unsigned short*)(ws + 184320);
    unsigned short* A_lo = A_hi + TSZ;
    unsigned short* B_hi = A_lo + TSZ;
    unsigned short* B_lo = B_hi + TSZ;

    hipMemsetAsync(packed, 0, BATCH * NLOC * sizeof(unsigned long long), stream);
    norm_kernel<<<dim3(BATCH * NLOC / 4), 256, 0, stream>>>(refsr, nr_inv);
    norm_kernel<<<dim3(BATCH * NLOC / 4), 256, 0, stream>>>(lrsr,  nl_inv);
    prep_kernel<<<dim3(600), 256, 0, stream>>>(refsr, A_hi, A_lo);
    prep_kernel<<<dim3(600), 256, 0, stream>>>(lrsr,  B_hi, B_lo);

    search_mfma<<<dim3(18, 18, BATCH), 256, 0, stream>>>(A_hi, A_lo, B_hi, B_lo, nr_inv, packed);

    finalize_kernel<<<dim3(36), 256, 0, stream>>>(packed, nl_inv, S_out, Rarg);

    transfer_kernel<256,  48,  3, 1, 1, 8><<<dim3(BATCH*(256/8)*48*48   / 256), 256, 0, stream>>>(ref3, Rarg, T3_out);
    transfer_kernel<128,  96,  6, 2, 2, 8><<<dim3(BATCH*(128/8)*96*96   / 256), 256, 0, stream>>>(ref2, Rarg, T2_out);
    transfer_kernel< 64, 192, 12, 4, 4, 8><<<dim3(BATCH*(64/8)*192*192  / 256), 256, 0, stream>>>(ref1, Rarg, T1_out);
}

// Round 3
// 608.776 us; speedup vs baseline: 1.4228x; 1.4228x over previous
//
#include <hip/hip_runtime.h>
#include <stdint.h>

#define L48   48
#define NLOC  2304      // 48*48
#define C3CH  256
#define KDIM  2304      // 256*9
#define BATCH 4
#define PADLOC 2400     // 50 rows * 48

typedef _Float16 half8 __attribute__((ext_vector_type(8)));
typedef float    floatx4 __attribute__((ext_vector_type(4)));
typedef unsigned short ushort8v __attribute__((ext_vector_type(8)));

union H16 { _Float16 f; unsigned short u; };

// ---------------- ss: per-pixel channel sum-of-squares (one (b,y) row per block) ----------------
__global__ __launch_bounds__(256) void ss_kernel(const float* __restrict__ img,
                                                 float* __restrict__ ss)
{
    __shared__ float sq[12288];          // [c][x] for one (b,y) row: 256*48 floats = 48 KB
    int bid = blockIdx.x;                // b*48 + y
    int b = bid / 48, y = bid - (bid / 48) * 48;
    const float* base = img + (size_t)b * C3CH * NLOC + y * L48;
    for (int flat = threadIdx.x; flat < 12288; flat += 256) {
        int c = flat / 48, x = flat - c * 48;
        float v = base[(size_t)c * NLOC + x];
        sq[flat] = v * v;
    }
    __syncthreads();
    int t = threadIdx.x;
    if (t < 48) {
        float a = 0.f;
        #pragma unroll 8
        for (int c = 0; c < C3CH; ++c) a += sq[c * 48 + t];
        ss[(size_t)b * NLOC + y * L48 + t] = a;
    }
}

// ---------------- norms: 3x3 stencil over ss map ----------------
__global__ __launch_bounds__(256) void norm_from_ss(const float* __restrict__ ss,
                                                    float* __restrict__ inv_norm)
{
    int i = blockIdx.x * 256 + threadIdx.x;
    if (i >= BATCH * NLOC) return;
    int b = i / NLOC, m = i - b * NLOC;
    int y = m / L48, x = m - y * L48;
    const float* s = ss + (size_t)b * NLOC;
    float a = 0.f;
    #pragma unroll
    for (int dy = -1; dy <= 1; ++dy) {
        int yy = y + dy;
        if ((unsigned)yy >= 48u) continue;
        #pragma unroll
        for (int dx = -1; dx <= 1; ++dx) {
            int xx = x + dx;
            if ((unsigned)xx >= 48u) continue;
            a += s[yy * L48 + xx];
        }
    }
    inv_norm[i] = 1.f / fmaxf(sqrtf(a), 1e-12f);
}

// ---------------- prep: fp32 image -> K-major granule split-fp16 (unchanged) ----------------
__global__ __launch_bounds__(256) void prep_kernel(const float* __restrict__ img,
                                                   unsigned short* __restrict__ out_hi,
                                                   unsigned short* __restrict__ out_lo)
{
    __shared__ unsigned short hi[256 * 50];
    __shared__ unsigned short lo[256 * 50];
    int bid = blockIdx.x;
    int oxIdx = bid / 200;
    int rem   = bid % 200;
    int b     = rem / 50;
    int yy    = rem % 50;
    int kj = oxIdx - 1;
    int y  = yy - 1;
    int t = threadIdx.x;
    bool yok = (unsigned)y < 48u;
    const float* ibase = img + (size_t)b * C3CH * NLOC;
    for (int flat = t; flat < 256 * 48; flat += 256) {
        int c = flat / 48;
        int x = flat - c * 48;
        int xs = x + kj;
        float v = 0.f;
        if (yok && (unsigned)xs < 48u)
            v = ibase[c * NLOC + y * L48 + xs];
        H16 h, l;
        h.f = (_Float16)v;
        float rvv = (v - (float)h.f) * 2048.0f;
        l.f = (_Float16)rvv;
        hi[c * 50 + x] = h.u;
        lo[c * 50 + x] = l.u;
    }
    __syncthreads();
    size_t plane = (size_t)(oxIdx * 4 + b);
    for (int flat = t; flat < 32 * 48; flat += 256) {
        int G = flat / 48;
        int x = flat - G * 48;
        ushort8v vh, vl;
        #pragma unroll
        for (int j = 0; j < 8; ++j) {
            vh[j] = hi[(G * 8 + j) * 50 + x];
            vl[j] = lo[(G * 8 + j) * 50 + x];
        }
        size_t o8 = ((plane * 32 + G) * PADLOC + (size_t)yy * 48 + x) * 8;
        *(ushort8v*)(out_hi + o8) = vh;
        *(ushort8v*)(out_lo + o8) = vl;
    }
}

// ---------------- search: fp16 hi/lo split MFMA GEMM (round-1 structure) ----------------
__device__ __forceinline__ void stage_arr(const unsigned short* __restrict__ gbase,
                                          int loc0,
                                          unsigned short* lbase,
                                          int wv, int lane)
{
    #pragma unroll
    for (int j = 0; j < 2; ++j) {
        int bg = (j * 4 + wv) * 64;          // base granule in [0,512)
        int q  = bg >> 7;
        int r0 = bg & 127;
        const unsigned short* gp = gbase + ((size_t)q * PADLOC + loc0 + r0 + lane) * 8;
        unsigned short* lp = lbase + (size_t)(bg + lane) * 8;
        __builtin_amdgcn_global_load_lds((const __attribute__((address_space(1))) void*)gp,
                                         (__attribute__((address_space(3))) void*)lp,
                                         16, 0, 0);
    }
}

__global__ __launch_bounds__(256, 2) void search_mfma(const unsigned short* __restrict__ At_hi,
                                                      const unsigned short* __restrict__ At_lo,
                                                      const unsigned short* __restrict__ Bt_hi,
                                                      const unsigned short* __restrict__ Bt_lo,
                                                      const float* __restrict__ nr_inv,
                                                      unsigned long long* __restrict__ packed)
{
    // 2 buffers x 4 arrays x 4096 ushorts (8KB) = 65536 B
    __shared__ __align__(16) unsigned short lds[2 * 4 * 4096];

    const int tid = threadIdx.x;
    const int b  = blockIdx.z;
    const int l0 = blockIdx.y * 128;
    const int m0 = blockIdx.x * 128;

    const int lane = tid & 63;
    const int wv = tid >> 6;          // wave id 0..3
    const int wr = tid >> 7;          // wave row 0..1
    const int wc = (tid >> 6) & 1;    // wave col 0..1
    const int mrow = lane & 15;
    const int q = lane >> 4;          // k-granule 0..3

    floatx4 acc1[4][4];
    floatx4 acc2[4][4];
    #pragma unroll
    for (int i = 0; i < 4; ++i)
        #pragma unroll
        for (int j = 0; j < 4; ++j) { acc1[i][j] = (floatx4)0.f; acc2[i][j] = (floatx4)0.f; }

    auto issue = [&](int it, int sel) {
        int o  = it >> 3;
        int cc = it & 7;
        int od3 = o / 3;
        int ki  = od3 - 1;
        int ox  = o - od3 * 3;
        int plane = ox * 4 + b;
        int locA = l0 + 48 * (1 + ki);
        int locB = m0 + 48 * (1 + ki);
        size_t gb = (size_t)(plane * 32 + cc * 4) * (PADLOC * 8);
        unsigned short* L = (unsigned short*)lds + sel * 16384;
        stage_arr(At_hi + gb, locA, L,         wv, lane);
        stage_arr(At_lo + gb, locA, L + 4096,  wv, lane);
        stage_arr(Bt_hi + gb, locB, L + 8192,  wv, lane);
        stage_arr(Bt_lo + gb, locB, L + 12288, wv, lane);
    };

    issue(0, 0);
    __syncthreads();   // drains vmcnt(0): buffer 0 ready

    for (int it = 0; it < 72; ++it) {
        const int sel = it & 1;
        if (it + 1 < 72) issue(it + 1, sel ^ 1);   // async prefetch overlaps this iter's compute

        const _Float16* L  = (const _Float16*)((unsigned short*)lds + sel * 16384);
        const _Float16* Ah = L;
        const _Float16* Al = L + 4096;
        const _Float16* Bh = L + 8192;
        const _Float16* Bl = L + 12288;

        half8 ahf[4], alf[4];
        #pragma unroll
        for (int fi = 0; fi < 4; ++fi) {
            int g = q * 128 + wr * 64 + fi * 16 + mrow;
            ahf[fi] = *(const half8*)(Ah + g * 8);
            alf[fi] = *(const half8*)(Al + g * 8);
        }
        #pragma unroll
        for (int fj = 0; fj < 4; ++fj) {
            int g = q * 128 + wc * 64 + fj * 16 + mrow;
            half8 bhf = *(const half8*)(Bh + g * 8);
            half8 blf = *(const half8*)(Bl + g * 8);
            #pragma unroll
            for (int fi = 0; fi < 4; ++fi) {
                acc1[fi][fj] = __builtin_amdgcn_mfma_f32_16x16x32_f16(ahf[fi], bhf, acc1[fi][fj], 0, 0, 0);
                acc2[fi][fj] = __builtin_amdgcn_mfma_f32_16x16x32_f16(ahf[fi], blf, acc2[fi][fj], 0, 0, 0);
                acc2[fi][fj] = __builtin_amdgcn_mfma_f32_16x16x32_f16(alf[fi], bhf, acc2[fi][fj], 0, 0, 0);
            }
        }
        __syncthreads();   // drains prefetch vmcnt + separates read of buf[sel] from its overwrite
    }

    // ---- epilogue: row-normalize, per-column argmax over l within block ----
    float* redv = (float*)lds;               // [8][128]
    int*   redi = (int*)(redv + 8 * 128);    // [8][128]

    const float inv2048 = 1.0f / 2048.0f;
    float bestv[4];
    int   besti[4];
    #pragma unroll
    for (int fj = 0; fj < 4; ++fj) { bestv[fj] = -1e30f; besti[fj] = 0; }

    #pragma unroll
    for (int fi = 0; fi < 4; ++fi) {
        int rowbase = l0 + wr * 64 + fi * 16 + (lane >> 4) * 4;
        #pragma unroll
        for (int r = 0; r < 4; ++r) {
            float rinv = nr_inv[b * NLOC + rowbase + r];
            #pragma unroll
            for (int fj = 0; fj < 4; ++fj) {
                float v = (acc1[fi][fj][r] + acc2[fi][fj][r] * inv2048) * rinv;
                if (v > bestv[fj]) { bestv[fj] = v; besti[fj] = rowbase + r; }
            }
        }
    }

    int cand = wr * 4 + (lane >> 4);   // 0..7
    #pragma unroll
    for (int fj = 0; fj < 4; ++fj) {
        int col = wc * 64 + fj * 16 + mrow;
        redv[cand * 128 + col] = bestv[fj];
        redi[cand * 128 + col] = besti[fj];
    }
    __syncthreads();
    if (tid < 128) {
        float best = redv[tid];
        int   bi   = redi[tid];
        #pragma unroll
        for (int c = 1; c < 8; ++c) {
            float v  = redv[c * 128 + tid];
            int   i2 = redi[c * 128 + tid];
            if (v > best || (v == best && i2 < bi)) { best = v; bi = i2; }
        }
        unsigned int sv = __float_as_uint(best);
        sv = (sv & 0x80000000u) ? ~sv : (sv | 0x80000000u);
        unsigned long long p = ((unsigned long long)sv << 32)
                             | (unsigned long long)(0xFFFFFFFFu - (unsigned)bi);
        atomicMax(packed + b * NLOC + m0 + tid, p);
    }
}

// ---------------- finalize: unpack S and argmax (unchanged) ----------------
__global__ __launch_bounds__(256) void finalize_kernel(const unsigned long long* __restrict__ packed,
                                                       const float* __restrict__ nl_inv,
                                                       float* __restrict__ S,
                                                       int* __restrict__ Rarg)
{
    int i = blockIdx.x * 256 + threadIdx.x;
    if (i >= BATCH * NLOC) return;
    unsigned long long p = packed[i];
    unsigned int sv   = (unsigned int)(p >> 32);
    unsigned int bits = (sv & 0x80000000u) ? (sv & 0x7FFFFFFFu) : ~sv;
    float val = __uint_as_float(bits);
    int   idx = (int)(0xFFFFFFFFu - (unsigned int)(p & 0xFFFFFFFFu));
    S[i]    = val * nl_inv[i];
    Rarg[i] = idx;
}

// ------------- transfer: fused gather + fold, fully unrolled 3x3, batched loads -------------
// The fold window is always <=3x3 candidate patches (K/S==3 for all levels).
// All 9 Rarg loads and all 9 gathers are issued unconditionally (clamped/masked),
// giving MLP of 9 instead of a serial load->wait->add chain.
template<int C, int H, int K, int S, int P>
__global__ __launch_bounds__(256) void transfer_kernel(const float* __restrict__ ref,
                                                       const int* __restrict__ Rarg,
                                                       float* __restrict__ out)
{
    int idx = blockIdx.x * 256 + threadIdx.x;
    if (idx >= BATCH * C * H * H) return;
    int x = idx % H;
    int y = (idx / H) % H;
    int c = (idx / (H * H)) % C;
    int b = idx / (H * H * C);
    int Y = y + P, X = x + P;
    int ylo = Y - K + 1; ylo = (ylo > 0) ? (ylo + S - 1) / S : 0;
    int yhi = Y / S; if (yhi > 47) yhi = 47;
    int xlo = X - K + 1; xlo = (xlo > 0) ? (xlo + S - 1) / S : 0;
    int xhi = X / S; if (xhi > 47) xhi = 47;
    const float* rbase = ref + ((size_t)b * C + c) * H * H;
    const int*   abase = Rarg + b * NLOC;

    // batched Rarg loads (clamped indices; invalid slots masked later)
    int qv[3][3];
    #pragma unroll
    for (int dy = 0; dy < 3; ++dy) {
        int py = ylo + dy; py = (py > 47) ? 47 : py;
        #pragma unroll
        for (int dx = 0; dx < 3; ++dx) {
            int px = xlo + dx; px = (px > 47) ? 47 : px;
            qv[dy][dx] = abase[py * L48 + px];
        }
    }

    float acc = 0.f;
    #pragma unroll
    for (int dy = 0; dy < 3; ++dy) {
        int py = ylo + dy;
        bool yok = (py <= yhi);
        int ki = Y - py * S;
        #pragma unroll
        for (int dx = 0; dx < 3; ++dx) {
            int px = xlo + dx;
            bool ok = yok && (px <= xhi);
            int kj = X - px * S;
            int qvv = qv[dy][dx];
            int qy = qvv / L48, qx = qvv - qy * L48;
            int row = qy * S + ki - P;
            int col = qx * S + kj - P;
            ok = ok && ((unsigned)row < (unsigned)H) && ((unsigned)col < (unsigned)H);
            int off = ok ? (row * H + col) : 0;
            float v = rbase[off];
            acc += ok ? v : 0.f;
        }
    }
    out[idx] = acc * (1.f / 9.f);
}

extern "C" void kernel_launch(void* const* d_in, const int* in_sizes, int n_in,
                              void* d_out, int out_size, void* d_ws, size_t ws_size,
                              hipStream_t stream)
{
    const float* lrsr  = (const float*)d_in[0];
    const float* refsr = (const float*)d_in[1];
    const float* ref1  = (const float*)d_in[2];
    const float* ref2  = (const float*)d_in[3];
    const float* ref3  = (const float*)d_in[4];

    float* S_out  = (float*)d_out;                   // 9216
    float* T3_out = S_out  + BATCH * NLOC;           // 2359296
    float* T2_out = T3_out + BATCH * 256 * 48 * 48;  // 4718592
    float* T1_out = T2_out + BATCH * 128 * 96 * 96;  // 9437184

    char* ws = (char*)d_ws;
    unsigned long long* packed = (unsigned long long*)ws;         // 73728 B
    float* nr_inv = (float*)(ws + 73728);                         // 36864 B
    float* nl_inv = (float*)(ws + 110592);                        // 36864 B
    int*   Rarg   = (int*)(ws + 147456);                          // 36864 B
    const size_t TSZ = (size_t)3 * BATCH * PADLOC * 256;          // 7372800 elements
    unsigned short* A_hi = (unsigned short*)(ws + 184320);
    unsigned short* A_lo = A_hi + TSZ;
    unsigned short* B_hi = A_lo + TSZ;
    unsigned short* B_lo = B_hi + TSZ;

    // ss scratch aliases 'packed' (2 x 9216 floats = 73728 B) BEFORE its memset
    float* ss_ref = (float*)packed;
    float* ss_lr  = ss_ref + BATCH * NLOC;

    ss_kernel<<<dim3(BATCH * 48), 256, 0, stream>>>(refsr, ss_ref);
    ss_kernel<<<dim3(BATCH * 48), 256, 0, stream>>>(lrsr,  ss_lr);
    norm_from_ss<<<dim3(36), 256, 0, stream>>>(ss_ref, nr_inv);
    norm_from_ss<<<dim3(36), 256, 0, stream>>>(ss_lr,  nl_inv);

    hipMemsetAsync(packed, 0, BATCH * NLOC * sizeof(unsigned long long), stream);
    prep_kernel<<<dim3(600), 256, 0, stream>>>(refsr, A_hi, A_lo);
    prep_kernel<<<dim3(600), 256, 0, stream>>>(lrsr,  B_hi, B_lo);

    search_mfma<<<dim3(18, 18, BATCH), 256, 0, stream>>>(A_hi, A_lo, B_hi, B_lo, nr_inv, packed);

    finalize_kernel<<<dim3(36), 256, 0, stream>>>(packed, nl_inv, S_out, Rarg);

    transfer_kernel<256,  48,  3, 1, 1><<<dim3(BATCH*256*48*48   / 256), 256, 0, stream>>>(ref3, Rarg, T3_out);
    transfer_kernel<128,  96,  6, 2, 2><<<dim3(BATCH*128*96*96   / 256), 256, 0, stream>>>(ref2, Rarg, T2_out);
    transfer_kernel< 64, 192, 12, 4, 4><<<dim3(BATCH*64*192*192  / 256), 256, 0, stream>>>(ref1, Rarg, T1_out);
}

// Round 4
// 581.324 us; speedup vs baseline: 1.4900x; 1.0472x over previous
//
#include <hip/hip_runtime.h>
#include <stdint.h>

#define L48   48
#define NLOC  2304      // 48*48
#define C3CH  256
#define KDIM  2304      // 256*9
#define BATCH 4
#define PADLOC 2400     // 50 rows * 48

typedef _Float16 half8 __attribute__((ext_vector_type(8)));
typedef float    floatx4 __attribute__((ext_vector_type(4)));
typedef unsigned short ushort8v __attribute__((ext_vector_type(8)));

union H16 { _Float16 f; unsigned short u; };

// ---------------- ss: per-pixel channel sum-of-squares ----------------
__global__ __launch_bounds__(256) void ss_kernel(const float* __restrict__ img,
                                                 float* __restrict__ ss)
{
    __shared__ float sq[12288];          // [c][x] for one (b,y) row
    __shared__ float part[192];
    int bid = blockIdx.x;                // b*48 + y
    int b = bid / 48, y = bid - (bid / 48) * 48;
    const float* base = img + (size_t)b * C3CH * NLOC + y * L48;
    for (int flat = threadIdx.x; flat < 12288; flat += 256) {
        int c = flat / 48, x = flat - c * 48;
        float v = base[(size_t)c * NLOC + x];
        sq[flat] = v * v;
    }
    __syncthreads();
    int t = threadIdx.x;
    if (t < 192) {
        int x = t >> 2, p = t & 3;
        float a = 0.f;
        #pragma unroll 8
        for (int c = p * 64; c < p * 64 + 64; ++c) a += sq[c * 48 + x];
        part[t] = a;
    }
    __syncthreads();
    if (t < 48)
        ss[(size_t)b * NLOC + y * L48 + t] =
            part[t * 4] + part[t * 4 + 1] + part[t * 4 + 2] + part[t * 4 + 3];
}

// ---------------- norms: 3x3 stencil over ss map ----------------
__global__ __launch_bounds__(256) void norm_from_ss(const float* __restrict__ ss,
                                                    float* __restrict__ inv_norm)
{
    int i = blockIdx.x * 256 + threadIdx.x;
    if (i >= BATCH * NLOC) return;
    int b = i / NLOC, m = i - b * NLOC;
    int y = m / L48, x = m - y * L48;
    const float* s = ss + (size_t)b * NLOC;
    float a = 0.f;
    #pragma unroll
    for (int dy = -1; dy <= 1; ++dy) {
        int yy = y + dy;
        if ((unsigned)yy >= 48u) continue;
        #pragma unroll
        for (int dx = -1; dx <= 1; ++dx) {
            int xx = x + dx;
            if ((unsigned)xx >= 48u) continue;
            a += s[yy * L48 + xx];
        }
    }
    inv_norm[i] = 1.f / fmaxf(sqrtf(a), 1e-12f);
}

// ---------------- prep: fp32 image -> K-major granule split-fp16, 3 ox shifts per block ----------------
// Reads each (b,y) row-slab once with a +-1 x-halo (50 cols) and emits all three
// ox variants from the same LDS tile. 200 blocks (was 600), 1/3 the global reads.
__global__ __launch_bounds__(256) void prep_kernel(const float* __restrict__ img,
                                                   unsigned short* __restrict__ out_hi,
                                                   unsigned short* __restrict__ out_lo)
{
    __shared__ unsigned short hi[256 * 50];   // [c][s], s = xs+1, xs in [-1,49)
    __shared__ unsigned short lo[256 * 50];
    int bid = blockIdx.x;        // b*50 + yy
    int b   = bid / 50;
    int yy  = bid - b * 50;
    int y   = yy - 1;
    int t = threadIdx.x;
    bool yok = (unsigned)y < 48u;
    const float* ibase = img + (size_t)b * C3CH * NLOC;
    for (int flat = t; flat < 256 * 50; flat += 256) {
        int c = flat / 50;
        int s = flat - c * 50;
        int xs = s - 1;
        float v = 0.f;
        if (yok && (unsigned)xs < 48u)
            v = ibase[c * NLOC + y * L48 + xs];
        H16 h, l;
        h.f = (_Float16)v;
        float rvv = (v - (float)h.f) * 2048.0f;
        l.f = (_Float16)rvv;
        hi[flat] = h.u;
        lo[flat] = l.u;
    }
    __syncthreads();
    #pragma unroll
    for (int ox = 0; ox < 3; ++ox) {
        size_t plane = (size_t)(ox * 4 + b);
        for (int flat = t; flat < 32 * 48; flat += 256) {
            int G = flat / 48;
            int x = flat - G * 48;
            ushort8v vh, vl;
            #pragma unroll
            for (int j = 0; j < 8; ++j) {
                vh[j] = hi[(G * 8 + j) * 50 + x + ox];
                vl[j] = lo[(G * 8 + j) * 50 + x + ox];
            }
            size_t o8 = ((plane * 32 + G) * PADLOC + (size_t)yy * 48 + x) * 8;
            *(ushort8v*)(out_hi + o8) = vh;
            *(ushort8v*)(out_lo + o8) = vl;
        }
    }
}

// ---------------- search: fp16 hi/lo split MFMA GEMM (round-3, known-good) ----------------
__device__ __forceinline__ void stage_arr(const unsigned short* __restrict__ gbase,
                                          int loc0,
                                          unsigned short* lbase,
                                          int wv, int lane)
{
    #pragma unroll
    for (int j = 0; j < 2; ++j) {
        int bg = (j * 4 + wv) * 64;          // base granule in [0,512)
        int q  = bg >> 7;
        int r0 = bg & 127;
        const unsigned short* gp = gbase + ((size_t)q * PADLOC + loc0 + r0 + lane) * 8;
        unsigned short* lp = lbase + (size_t)(bg + lane) * 8;
        __builtin_amdgcn_global_load_lds((const __attribute__((address_space(1))) void*)gp,
                                         (__attribute__((address_space(3))) void*)lp,
                                         16, 0, 0);
    }
}

__global__ __launch_bounds__(256, 2) void search_mfma(const unsigned short* __restrict__ At_hi,
                                                      const unsigned short* __restrict__ At_lo,
                                                      const unsigned short* __restrict__ Bt_hi,
                                                      const unsigned short* __restrict__ Bt_lo,
                                                      const float* __restrict__ nr_inv,
                                                      unsigned long long* __restrict__ packed)
{
    // 2 buffers x 4 arrays x 4096 ushorts (8KB) = 65536 B
    __shared__ __align__(16) unsigned short lds[2 * 4 * 4096];

    const int tid = threadIdx.x;
    const int b  = blockIdx.z;
    const int l0 = blockIdx.y * 128;
    const int m0 = blockIdx.x * 128;

    const int lane = tid & 63;
    const int wv = tid >> 6;          // wave id 0..3
    const int wr = tid >> 7;          // wave row 0..1
    const int wc = (tid >> 6) & 1;    // wave col 0..1
    const int mrow = lane & 15;
    const int q = lane >> 4;          // k-granule 0..3

    floatx4 acc1[4][4];
    floatx4 acc2[4][4];
    #pragma unroll
    for (int i = 0; i < 4; ++i)
        #pragma unroll
        for (int j = 0; j < 4; ++j) { acc1[i][j] = (floatx4)0.f; acc2[i][j] = (floatx4)0.f; }

    auto issue = [&](int it, int sel) {
        int o  = it >> 3;
        int cc = it & 7;
        int od3 = o / 3;
        int ki  = od3 - 1;
        int ox  = o - od3 * 3;
        int plane = ox * 4 + b;
        int locA = l0 + 48 * (1 + ki);
        int locB = m0 + 48 * (1 + ki);
        size_t gb = (size_t)(plane * 32 + cc * 4) * (PADLOC * 8);
        unsigned short* L = (unsigned short*)lds + sel * 16384;
        stage_arr(At_hi + gb, locA, L,         wv, lane);
        stage_arr(At_lo + gb, locA, L + 4096,  wv, lane);
        stage_arr(Bt_hi + gb, locB, L + 8192,  wv, lane);
        stage_arr(Bt_lo + gb, locB, L + 12288, wv, lane);
    };

    issue(0, 0);
    __syncthreads();   // drains vmcnt(0): buffer 0 ready

    for (int it = 0; it < 72; ++it) {
        const int sel = it & 1;
        if (it + 1 < 72) issue(it + 1, sel ^ 1);   // async prefetch overlaps this iter's compute

        const _Float16* L  = (const _Float16*)((unsigned short*)lds + sel * 16384);
        const _Float16* Ah = L;
        const _Float16* Al = L + 4096;
        const _Float16* Bh = L + 8192;
        const _Float16* Bl = L + 12288;

        half8 ahf[4], alf[4];
        #pragma unroll
        for (int fi = 0; fi < 4; ++fi) {
            int g = q * 128 + wr * 64 + fi * 16 + mrow;
            ahf[fi] = *(const half8*)(Ah + g * 8);
            alf[fi] = *(const half8*)(Al + g * 8);
        }
        #pragma unroll
        for (int fj = 0; fj < 4; ++fj) {
            int g = q * 128 + wc * 64 + fj * 16 + mrow;
            half8 bhf = *(const half8*)(Bh + g * 8);
            half8 blf = *(const half8*)(Bl + g * 8);
            #pragma unroll
            for (int fi = 0; fi < 4; ++fi) {
                acc1[fi][fj] = __builtin_amdgcn_mfma_f32_16x16x32_f16(ahf[fi], bhf, acc1[fi][fj], 0, 0, 0);
                acc2[fi][fj] = __builtin_amdgcn_mfma_f32_16x16x32_f16(ahf[fi], blf, acc2[fi][fj], 0, 0, 0);
                acc2[fi][fj] = __builtin_amdgcn_mfma_f32_16x16x32_f16(alf[fi], bhf, acc2[fi][fj], 0, 0, 0);
            }
        }
        __syncthreads();   // drains prefetch vmcnt + separates read of buf[sel] from its overwrite
    }

    // ---- epilogue: row-normalize, per-column argmax over l within block ----
    float* redv = (float*)lds;               // [8][128]
    int*   redi = (int*)(redv + 8 * 128);    // [8][128]

    const float inv2048 = 1.0f / 2048.0f;
    float bestv[4];
    int   besti[4];
    #pragma unroll
    for (int fj = 0; fj < 4; ++fj) { bestv[fj] = -1e30f; besti[fj] = 0; }

    #pragma unroll
    for (int fi = 0; fi < 4; ++fi) {
        int rowbase = l0 + wr * 64 + fi * 16 + (lane >> 4) * 4;
        #pragma unroll
        for (int r = 0; r < 4; ++r) {
            float rinv = nr_inv[b * NLOC + rowbase + r];
            #pragma unroll
            for (int fj = 0; fj < 4; ++fj) {
                float v = (acc1[fi][fj][r] + acc2[fi][fj][r] * inv2048) * rinv;
                if (v > bestv[fj]) { bestv[fj] = v; besti[fj] = rowbase + r; }
            }
        }
    }

    int cand = wr * 4 + (lane >> 4);   // 0..7
    #pragma unroll
    for (int fj = 0; fj < 4; ++fj) {
        int col = wc * 64 + fj * 16 + mrow;
        redv[cand * 128 + col] = bestv[fj];
        redi[cand * 128 + col] = besti[fj];
    }
    __syncthreads();
    if (tid < 128) {
        float best = redv[tid];
        int   bi   = redi[tid];
        #pragma unroll
        for (int c = 1; c < 8; ++c) {
            float v  = redv[c * 128 + tid];
            int   i2 = redi[c * 128 + tid];
            if (v > best || (v == best && i2 < bi)) { best = v; bi = i2; }
        }
        unsigned int sv = __float_as_uint(best);
        sv = (sv & 0x80000000u) ? ~sv : (sv | 0x80000000u);
        unsigned long long p = ((unsigned long long)sv << 32)
                             | (unsigned long long)(0xFFFFFFFFu - (unsigned)bi);
        atomicMax(packed + b * NLOC + m0 + tid, p);
    }
}

// ---------------- finalize: unpack S and argmax (unchanged) ----------------
__global__ __launch_bounds__(256) void finalize_kernel(const unsigned long long* __restrict__ packed,
                                                       const float* __restrict__ nl_inv,
                                                       float* __restrict__ S,
                                                       int* __restrict__ Rarg)
{
    int i = blockIdx.x * 256 + threadIdx.x;
    if (i >= BATCH * NLOC) return;
    unsigned long long p = packed[i];
    unsigned int sv   = (unsigned int)(p >> 32);
    unsigned int bits = (sv & 0x80000000u) ? (sv & 0x7FFFFFFFu) : ~sv;
    float val = __uint_as_float(bits);
    int   idx = (int)(0xFFFFFFFFu - (unsigned int)(p & 0xFFFFFFFFu));
    S[i]    = val * nl_inv[i];
    Rarg[i] = idx;
}

// ------------- transfer: fused gather + fold, S-wide vectorized -------------
// For all levels K=3S, P=S. For an S-aligned run of S output pixels the candidate
// window is identical (px in [u-2,u], u=xq+1) and col = x0 + S*(qy-px) is S-aligned,
// so one thread computes S pixels with 9 shared Rarg loads and 9 aligned vector
// gathers + one bounds check per candidate. row = y + S*(qy-py).
template<int N> struct VecT;
template<> struct VecT<1> { using type = float; };
template<> struct VecT<2> { using type = float __attribute__((ext_vector_type(2))); };
template<> struct VecT<4> { using type = float __attribute__((ext_vector_type(4))); };

template<int C, int H, int S>
__global__ __launch_bounds__(256) void transfer_vec(const float* __restrict__ ref,
                                                    const int* __restrict__ Rarg,
                                                    float* __restrict__ out)
{
    using fvec = typename VecT<S>::type;
    int idx = blockIdx.x * 256 + threadIdx.x;   // grid exactly B*C*H*48/256
    int xq = idx % 48;
    int y  = (idx / 48) % H;
    int c  = (idx / (48 * H)) % C;
    int b  = idx / (48 * H * C);
    int x0 = xq * S;

    int u = xq + 1;
    int xlo = (u - 2 > 0) ? u - 2 : 0;
    int xhi = (u < 47) ? u : 47;
    int v = y / S + 1;
    int ylo = (v - 2 > 0) ? v - 2 : 0;
    int yhi = (v < 47) ? v : 47;

    const float* rbase = ref + ((size_t)b * C + c) * H * H;
    const int*   abase = Rarg + b * NLOC;

    // batched Rarg loads (clamped; invalid slots masked later)
    int qv[3][3];
    #pragma unroll
    for (int dy = 0; dy < 3; ++dy) {
        int py = ylo + dy; py = (py > 47) ? 47 : py;
        #pragma unroll
        for (int dx = 0; dx < 3; ++dx) {
            int px = xlo + dx; px = (px > 47) ? 47 : px;
            qv[dy][dx] = abase[py * L48 + px];
        }
    }

    fvec acc = (fvec)(0.f);
    #pragma unroll
    for (int dy = 0; dy < 3; ++dy) {
        int py = ylo + dy;
        bool yok = (py <= yhi);
        #pragma unroll
        for (int dx = 0; dx < 3; ++dx) {
            int px = xlo + dx;
            bool ok = yok && (px <= xhi);
            int q  = qv[dy][dx];
            int qy = q / L48, qx = q - qy * L48;
            int row = y  + S * (qy - py);
            int cb  = x0 + S * (qx - px);
            ok = ok && ((unsigned)row < (unsigned)H) && ((unsigned)cb < (unsigned)H);
            int off = ok ? (row * H + cb) : 0;
            fvec val = *(const fvec*)(rbase + off);
            acc += ok ? val : (fvec)(0.f);
        }
    }
    *(fvec*)(out + ((size_t)b * C + c) * H * H + (size_t)y * H + x0) = acc * (1.f / 9.f);
}

extern "C" void kernel_launch(void* const* d_in, const int* in_sizes, int n_in,
                              void* d_out, int out_size, void* d_ws, size_t ws_size,
                              hipStream_t stream)
{
    const float* lrsr  = (const float*)d_in[0];
    const float* refsr = (const float*)d_in[1];
    const float* ref1  = (const float*)d_in[2];
    const float* ref2  = (const float*)d_in[3];
    const float* ref3  = (const float*)d_in[4];

    float* S_out  = (float*)d_out;                   // 9216
    float* T3_out = S_out  + BATCH * NLOC;           // 2359296
    float* T2_out = T3_out + BATCH * 256 * 48 * 48;  // 4718592
    float* T1_out = T2_out + BATCH * 128 * 96 * 96;  // 9437184

    char* ws = (char*)d_ws;
    unsigned long long* packed = (unsigned long long*)ws;         // 73728 B
    float* nr_inv = (float*)(ws + 73728);                         // 36864 B
    float* nl_inv = (float*)(ws + 110592);                        // 36864 B
    int*   Rarg   = (int*)(ws + 147456);                          // 36864 B
    const size_t TSZ = (size_t)3 * BATCH * PADLOC * 256;          // 7372800 elements
    unsigned short* A_hi = (unsigned short*)(ws + 184320);
    unsigned short* A_lo = A_hi + TSZ;
    unsigned short* B_hi = A_lo + TSZ;
    unsigned short* B_lo = B_hi + TSZ;

    // ss scratch aliases 'packed' (2 x 9216 floats = 73728 B) BEFORE its memset
    float* ss_ref = (float*)packed;
    float* ss_lr  = ss_ref + BATCH * NLOC;

    ss_kernel<<<dim3(BATCH * 48), 256, 0, stream>>>(refsr, ss_ref);
    ss_kernel<<<dim3(BATCH * 48), 256, 0, stream>>>(lrsr,  ss_lr);
    norm_from_ss<<<dim3(36), 256, 0, stream>>>(ss_ref, nr_inv);
    norm_from_ss<<<dim3(36), 256, 0, stream>>>(ss_lr,  nl_inv);

    hipMemsetAsync(packed, 0, BATCH * NLOC * sizeof(unsigned long long), stream);
    prep_kernel<<<dim3(200), 256, 0, stream>>>(refsr, A_hi, A_lo);
    prep_kernel<<<dim3(200), 256, 0, stream>>>(lrsr,  B_hi, B_lo);

    search_mfma<<<dim3(18, 18, BATCH), 256, 0, stream>>>(A_hi, A_lo, B_hi, B_lo, nr_inv, packed);

    finalize_kernel<<<dim3(36), 256, 0, stream>>>(packed, nl_inv, S_out, Rarg);

    transfer_vec<256,  48, 1><<<dim3(9216), 256, 0, stream>>>(ref3, Rarg, T3_out);
    transfer_vec<128,  96, 2><<<dim3(9216), 256, 0, stream>>>(ref2, Rarg, T2_out);
    transfer_vec< 64, 192, 4><<<dim3(9216), 256, 0, stream>>>(ref1, Rarg, T1_out);
}

// Round 5
// 566.818 us; speedup vs baseline: 1.5281x; 1.0256x over previous
//
#include <hip/hip_runtime.h>
#include <stdint.h>

#define L48   48
#define NLOC  2304      // 48*48
#define C3CH  256
#define BATCH 4

typedef _Float16 half8 __attribute__((ext_vector_type(8)));
typedef float    floatx4 __attribute__((ext_vector_type(4)));
typedef unsigned short ushort8v __attribute__((ext_vector_type(8)));

union H16 { _Float16 f; unsigned short u; };

// ---------------- ss: per-pixel channel sum-of-squares ----------------
__global__ __launch_bounds__(256) void ss_kernel(const float* __restrict__ img,
                                                 float* __restrict__ ss)
{
    __shared__ float sq[12288];          // [c][x] for one (b,y) row
    __shared__ float part[192];
    int bid = blockIdx.x;                // b*48 + y
    int b = bid / 48, y = bid - (bid / 48) * 48;
    const float* base = img + (size_t)b * C3CH * NLOC + y * L48;
    for (int flat = threadIdx.x; flat < 12288; flat += 256) {
        int c = flat / 48, x = flat - c * 48;
        float v = base[(size_t)c * NLOC + x];
        sq[flat] = v * v;
    }
    __syncthreads();
    int t = threadIdx.x;
    if (t < 192) {
        int x = t >> 2, p = t & 3;
        float a = 0.f;
        #pragma unroll 8
        for (int c = p * 64; c < p * 64 + 64; ++c) a += sq[c * 48 + x];
        part[t] = a;
    }
    __syncthreads();
    if (t < 48)
        ss[(size_t)b * NLOC + y * L48 + t] =
            part[t * 4] + part[t * 4 + 1] + part[t * 4 + 2] + part[t * 4 + 3];
}

// ---------------- norms: 3x3 stencil over ss map ----------------
__global__ __launch_bounds__(256) void norm_from_ss(const float* __restrict__ ss,
                                                    float* __restrict__ inv_norm)
{
    int i = blockIdx.x * 256 + threadIdx.x;
    if (i >= BATCH * NLOC) return;
    int b = i / NLOC, m = i - b * NLOC;
    int y = m / L48, x = m - y * L48;
    const float* s = ss + (size_t)b * NLOC;
    float a = 0.f;
    #pragma unroll
    for (int dy = -1; dy <= 1; ++dy) {
        int yy = y + dy;
        if ((unsigned)yy >= 48u) continue;
        #pragma unroll
        for (int dx = -1; dx <= 1; ++dx) {
            int xx = x + dx;
            if ((unsigned)xx >= 48u) continue;
            a += s[yy * L48 + xx];
        }
    }
    inv_norm[i] = 1.f / fmaxf(sqrtf(a), 1e-12f);
}

// ---------------- prep: fp32 image -> K-major granule split-fp16 (no shifts, no pad) ----------------
// Layout per array: granule index (b*32 + G) over NLOC locations:
//   out[((b*32+G)*NLOC + loc)*8 + j] = fp16 of img[8G+j][loc], loc = y*48+x.
__global__ __launch_bounds__(256) void prep_kernel(const float* __restrict__ img,
                                                   unsigned short* __restrict__ out_hi,
                                                   unsigned short* __restrict__ out_lo)
{
    __shared__ unsigned short hi[256 * 48];
    __shared__ unsigned short lo[256 * 48];
    int bid = blockIdx.x;        // b*48 + y
    int b   = bid / 48;
    int y   = bid - b * 48;
    int t = threadIdx.x;
    const float* ibase = img + (size_t)b * C3CH * NLOC + (size_t)y * L48;
    for (int flat = t; flat < 256 * 48; flat += 256) {
        int c = flat / 48;
        int x = flat - c * 48;
        float v = ibase[(size_t)c * NLOC + x];
        H16 h, l;
        h.f = (_Float16)v;
        float rvv = (v - (float)h.f) * 2048.0f;
        l.f = (_Float16)rvv;
        hi[flat] = h.u;
        lo[flat] = l.u;
    }
    __syncthreads();
    for (int flat = t; flat < 32 * 48; flat += 256) {
        int G = flat / 48;
        int x = flat - G * 48;
        ushort8v vh, vl;
        #pragma unroll
        for (int j = 0; j < 8; ++j) {
            vh[j] = hi[(G * 8 + j) * 48 + x];
            vl[j] = lo[(G * 8 + j) * 48 + x];
        }
        size_t o8 = ((size_t)(b * 32 + G) * NLOC + (size_t)y * 48 + x) * 8;
        *(ushort8v*)(out_hi + o8) = vh;
        *(ushort8v*)(out_lo + o8) = vl;
    }
}

// ---------------- pass 1: pixel-correlation GEMM D = ref^T * lr (K=256), hi/lo split fp16 ----------------
__device__ __forceinline__ void stage_arr(const unsigned short* __restrict__ gbase,
                                          int loc0,
                                          unsigned short* lbase,
                                          int wv, int lane)
{
    #pragma unroll
    for (int j = 0; j < 2; ++j) {
        int bg = (j * 4 + wv) * 64;          // base granule in [0,512)
        int q  = bg >> 7;
        int r0 = bg & 127;
        const unsigned short* gp = gbase + ((size_t)q * NLOC + loc0 + r0 + lane) * 8;
        unsigned short* lp = lbase + (size_t)(bg + lane) * 8;
        __builtin_amdgcn_global_load_lds((const __attribute__((address_space(1))) void*)gp,
                                         (__attribute__((address_space(3))) void*)lp,
                                         16, 0, 0);
    }
}

__global__ __launch_bounds__(256, 2) void dgemm_mfma(const unsigned short* __restrict__ At_hi,
                                                     const unsigned short* __restrict__ At_lo,
                                                     const unsigned short* __restrict__ Bt_hi,
                                                     const unsigned short* __restrict__ Bt_lo,
                                                     int b,
                                                     float* __restrict__ D)
{
    // 2 buffers x 4 arrays x 4096 ushorts (8KB) = 65536 B
    __shared__ __align__(16) unsigned short lds[2 * 4 * 4096];

    const int tid = threadIdx.x;
    const int l0 = blockIdx.y * 128;   // ref rows
    const int m0 = blockIdx.x * 128;   // lr cols

    const int lane = tid & 63;
    const int wv = tid >> 6;          // wave id 0..3
    const int wr = tid >> 7;          // wave row 0..1
    const int wc = (tid >> 6) & 1;    // wave col 0..1
    const int mrow = lane & 15;
    const int q = lane >> 4;          // k-granule 0..3

    floatx4 acc1[4][4];
    floatx4 acc2[4][4];
    #pragma unroll
    for (int i = 0; i < 4; ++i)
        #pragma unroll
        for (int j = 0; j < 4; ++j) { acc1[i][j] = (floatx4)0.f; acc2[i][j] = (floatx4)0.f; }

    auto issue = [&](int it, int sel) {
        int cc = it;                                   // 32-channel chunk 0..7
        size_t gb = (size_t)(b * 32 + cc * 4) * ((size_t)NLOC * 8);
        unsigned short* L = (unsigned short*)lds + sel * 16384;
        stage_arr(At_hi + gb, l0, L,         wv, lane);
        stage_arr(At_lo + gb, l0, L + 4096,  wv, lane);
        stage_arr(Bt_hi + gb, m0, L + 8192,  wv, lane);
        stage_arr(Bt_lo + gb, m0, L + 12288, wv, lane);
    };

    issue(0, 0);
    __syncthreads();   // drains vmcnt(0): buffer 0 ready

    for (int it = 0; it < 8; ++it) {
        const int sel = it & 1;
        if (it + 1 < 8) issue(it + 1, sel ^ 1);   // async prefetch overlaps this iter's compute

        const _Float16* L  = (const _Float16*)((unsigned short*)lds + sel * 16384);
        const _Float16* Ah = L;
        const _Float16* Al = L + 4096;
        const _Float16* Bh = L + 8192;
        const _Float16* Bl = L + 12288;

        half8 ahf[4], alf[4];
        #pragma unroll
        for (int fi = 0; fi < 4; ++fi) {
            int g = q * 128 + wr * 64 + fi * 16 + mrow;
            ahf[fi] = *(const half8*)(Ah + g * 8);
            alf[fi] = *(const half8*)(Al + g * 8);
        }
        #pragma unroll
        for (int fj = 0; fj < 4; ++fj) {
            int g = q * 128 + wc * 64 + fj * 16 + mrow;
            half8 bhf = *(const half8*)(Bh + g * 8);
            half8 blf = *(const half8*)(Bl + g * 8);
            #pragma unroll
            for (int fi = 0; fi < 4; ++fi) {
                acc1[fi][fj] = __builtin_amdgcn_mfma_f32_16x16x32_f16(ahf[fi], bhf, acc1[fi][fj], 0, 0, 0);
                acc2[fi][fj] = __builtin_amdgcn_mfma_f32_16x16x32_f16(ahf[fi], blf, acc2[fi][fj], 0, 0, 0);
                acc2[fi][fj] = __builtin_amdgcn_mfma_f32_16x16x32_f16(alf[fi], bhf, acc2[fi][fj], 0, 0, 0);
            }
        }
        __syncthreads();
    }

    // ---- epilogue: write D tile (same row/col mapping as the verified argmax epilogue) ----
    const float inv2048 = 1.0f / 2048.0f;
    #pragma unroll
    for (int fi = 0; fi < 4; ++fi) {
        int rowbase = l0 + wr * 64 + fi * 16 + (lane >> 4) * 4;
        #pragma unroll
        for (int r = 0; r < 4; ++r) {
            int row = rowbase + r;
            #pragma unroll
            for (int fj = 0; fj < 4; ++fj) {
                int col = m0 + wc * 64 + fj * 16 + mrow;
                D[(size_t)row * NLOC + col] = acc1[fi][fj][r] + acc2[fi][fj][r] * inv2048;
            }
        }
    }
}

// ---------------- pass 2: diagonal 3x3 stencil on D + row-normalize + argmax ----------------
// R[(ly,lx),(my,mx)] = sum_{dy,dx in [-1,1]} D[(ly+dy)*48+lx+dx, (my+dy)*48+mx+dx]  (0 if OOB)
// Block = (my, ly-chunk). Stages 3 slices D[(ly+dy, my+dy)][48x48] per ly. Fused argmax -> packed atomicMax.
#define LCH 4
__global__ __launch_bounds__(256) void stencil_argmax(const float* __restrict__ D,
                                                      const float* __restrict__ nr_inv,
                                                      int b,
                                                      unsigned long long* __restrict__ packed)
{
    __shared__ float S[3][2304];
    const int my  = blockIdx.x;
    const int ly0 = blockIdx.y * LCH;
    const int t   = threadIdx.x;

    float bestv[9];
    int   besti[9];
    #pragma unroll
    for (int k = 0; k < 9; ++k) { bestv[k] = -1e30f; besti[k] = 0; }

    for (int ly = ly0; ly < ly0 + LCH; ++ly) {
        // load 3 slices (u = ly+dy-1, v = my+dy-1); zero if OOB
        #pragma unroll
        for (int dy = 0; dy < 3; ++dy) {
            int u = ly + dy - 1;
            int v = my + dy - 1;
            bool ok = ((unsigned)u < 48u) && ((unsigned)v < 48u);
            const float* dp = D + ((size_t)u * 48) * NLOC + (size_t)v * 48;
            for (int flat = t; flat < 2304; flat += 256) {
                int lxp = flat / 48, mxp = flat - lxp * 48;
                S[dy][flat] = ok ? dp[(size_t)lxp * NLOC + mxp] : 0.f;
            }
        }
        __syncthreads();

        #pragma unroll
        for (int k = 0; k < 9; ++k) {
            int p  = t + 256 * k;
            int lx = p / 48, mx = p - lx * 48;
            float s = 0.f;
            #pragma unroll
            for (int dy = 0; dy < 3; ++dy) {
                #pragma unroll
                for (int dx = 0; dx < 3; ++dx) {
                    int xl = lx + dx - 1;
                    int xm = mx + dx - 1;
                    bool ok = ((unsigned)xl < 48u) && ((unsigned)xm < 48u);
                    float v = S[dy][ok ? (xl * 48 + xm) : 0];
                    s += ok ? v : 0.f;
                }
            }
            float v = s * nr_inv[b * NLOC + ly * 48 + lx];
            if (v > bestv[k]) { bestv[k] = v; besti[k] = ly * 48 + lx; }
        }
        __syncthreads();   // before slices are overwritten next ly
    }

    // ---- block reduce over lx, then atomic merge over chunks ----
    float* redv = &S[0][0];
    int*   redi = (int*)&S[1][0];
    #pragma unroll
    for (int k = 0; k < 9; ++k) {
        int p = t + 256 * k;
        redv[p] = bestv[k];
        redi[p] = besti[k];
    }
    __syncthreads();
    if (t < 48) {
        int mx = t;
        float best = -1e30f;
        int   bi   = 0x7FFFFFFF;
        for (int lx = 0; lx < 48; ++lx) {
            float v  = redv[lx * 48 + mx];
            int   i2 = redi[lx * 48 + mx];
            if (v > best || (v == best && i2 < bi)) { best = v; bi = i2; }
        }
        unsigned int sv = __float_as_uint(best);
        sv = (sv & 0x80000000u) ? ~sv : (sv | 0x80000000u);
        unsigned long long pk = ((unsigned long long)sv << 32)
                              | (unsigned long long)(0xFFFFFFFFu - (unsigned)bi);
        atomicMax(packed + b * NLOC + my * 48 + mx, pk);
    }
}

// ---------------- finalize: unpack S and argmax (unchanged) ----------------
__global__ __launch_bounds__(256) void finalize_kernel(const unsigned long long* __restrict__ packed,
                                                       const float* __restrict__ nl_inv,
                                                       float* __restrict__ S,
                                                       int* __restrict__ Rarg)
{
    int i = blockIdx.x * 256 + threadIdx.x;
    if (i >= BATCH * NLOC) return;
    unsigned long long p = packed[i];
    unsigned int sv   = (unsigned int)(p >> 32);
    unsigned int bits = (sv & 0x80000000u) ? (sv & 0x7FFFFFFFu) : ~sv;
    float val = __uint_as_float(bits);
    int   idx = (int)(0xFFFFFFFFu - (unsigned int)(p & 0xFFFFFFFFu));
    S[i]    = val * nl_inv[i];
    Rarg[i] = idx;
}

// ------------- transfer: fused gather + fold, S-wide vectorized (round-4, known-good) -------------
template<int N> struct VecT;
template<> struct VecT<1> { using type = float; };
template<> struct VecT<2> { using type = float __attribute__((ext_vector_type(2))); };
template<> struct VecT<4> { using type = float __attribute__((ext_vector_type(4))); };

template<int C, int H, int S>
__global__ __launch_bounds__(256) void transfer_vec(const float* __restrict__ ref,
                                                    const int* __restrict__ Rarg,
                                                    float* __restrict__ out)
{
    using fvec = typename VecT<S>::type;
    int idx = blockIdx.x * 256 + threadIdx.x;   // grid exactly B*C*H*48/256
    int xq = idx % 48;
    int y  = (idx / 48) % H;
    int c  = (idx / (48 * H)) % C;
    int b  = idx / (48 * H * C);
    int x0 = xq * S;

    int u = xq + 1;
    int xlo = (u - 2 > 0) ? u - 2 : 0;
    int xhi = (u < 47) ? u : 47;
    int v = y / S + 1;
    int ylo = (v - 2 > 0) ? v - 2 : 0;
    int yhi = (v < 47) ? v : 47;

    const float* rbase = ref + ((size_t)b * C + c) * H * H;
    const int*   abase = Rarg + b * NLOC;

    int qv[3][3];
    #pragma unroll
    for (int dy = 0; dy < 3; ++dy) {
        int py = ylo + dy; py = (py > 47) ? 47 : py;
        #pragma unroll
        for (int dx = 0; dx < 3; ++dx) {
            int px = xlo + dx; px = (px > 47) ? 47 : px;
            qv[dy][dx] = abase[py * L48 + px];
        }
    }

    fvec acc = (fvec)(0.f);
    #pragma unroll
    for (int dy = 0; dy < 3; ++dy) {
        int py = ylo + dy;
        bool yok = (py <= yhi);
        #pragma unroll
        for (int dx = 0; dx < 3; ++dx) {
            int px = xlo + dx;
            bool ok = yok && (px <= xhi);
            int q  = qv[dy][dx];
            int qy = q / L48, qx = q - qy * L48;
            int row = y  + S * (qy - py);
            int cb  = x0 + S * (qx - px);
            ok = ok && ((unsigned)row < (unsigned)H) && ((unsigned)cb < (unsigned)H);
            int off = ok ? (row * H + cb) : 0;
            fvec val = *(const fvec*)(rbase + off);
            acc += ok ? val : (fvec)(0.f);
        }
    }
    *(fvec*)(out + ((size_t)b * C + c) * H * H + (size_t)y * H + x0) = acc * (1.f / 9.f);
}

extern "C" void kernel_launch(void* const* d_in, const int* in_sizes, int n_in,
                              void* d_out, int out_size, void* d_ws, size_t ws_size,
                              hipStream_t stream)
{
    const float* lrsr  = (const float*)d_in[0];
    const float* refsr = (const float*)d_in[1];
    const float* ref1  = (const float*)d_in[2];
    const float* ref2  = (const float*)d_in[3];
    const float* ref3  = (const float*)d_in[4];

    float* S_out  = (float*)d_out;                   // 9216
    float* T3_out = S_out  + BATCH * NLOC;           // 2359296
    float* T2_out = T3_out + BATCH * 256 * 48 * 48;  // 4718592
    float* T1_out = T2_out + BATCH * 128 * 96 * 96;  // 9437184

    char* ws = (char*)d_ws;
    unsigned long long* packed = (unsigned long long*)ws;         // 73728 B
    float* nr_inv = (float*)(ws + 73728);                         // 36864 B
    float* nl_inv = (float*)(ws + 110592);                        // 36864 B
    int*   Rarg   = (int*)(ws + 147456);                          // 36864 B
    const size_t ASZ = (size_t)BATCH * NLOC * C3CH;               // 2359296 ushorts (4.72 MB)
    unsigned short* A_hi = (unsigned short*)(ws + 184320);
    unsigned short* A_lo = A_hi + ASZ;
    unsigned short* B_hi = A_lo + ASZ;
    unsigned short* B_lo = B_hi + ASZ;
    float* D = (float*)(ws + 184320 + 4 * ASZ * sizeof(unsigned short));  // 21.2 MB, one batch

    // ss scratch aliases 'packed' BEFORE its memset
    float* ss_ref = (float*)packed;
    float* ss_lr  = ss_ref + BATCH * NLOC;

    ss_kernel<<<dim3(BATCH * 48), 256, 0, stream>>>(refsr, ss_ref);
    ss_kernel<<<dim3(BATCH * 48), 256, 0, stream>>>(lrsr,  ss_lr);
    norm_from_ss<<<dim3(36), 256, 0, stream>>>(ss_ref, nr_inv);
    norm_from_ss<<<dim3(36), 256, 0, stream>>>(ss_lr,  nl_inv);

    hipMemsetAsync(packed, 0, BATCH * NLOC * sizeof(unsigned long long), stream);
    prep_kernel<<<dim3(BATCH * 48), 256, 0, stream>>>(refsr, A_hi, A_lo);
    prep_kernel<<<dim3(BATCH * 48), 256, 0, stream>>>(lrsr,  B_hi, B_lo);

    for (int b = 0; b < BATCH; ++b) {
        dgemm_mfma<<<dim3(18, 18), 256, 0, stream>>>(A_hi, A_lo, B_hi, B_lo, b, D);
        stencil_argmax<<<dim3(48, 48 / LCH), 256, 0, stream>>>(D, nr_inv, b, packed);
    }

    finalize_kernel<<<dim3(36), 256, 0, stream>>>(packed, nl_inv, S_out, Rarg);

    transfer_vec<256,  48, 1><<<dim3(9216), 256, 0, stream>>>(ref3, Rarg, T3_out);
    transfer_vec<128,  96, 2><<<dim3(9216), 256, 0, stream>>>(ref2, Rarg, T2_out);
    transfer_vec< 64, 192, 4><<<dim3(9216), 256, 0, stream>>>(ref1, Rarg, T1_out);
}

// Round 6
// 520.857 us; speedup vs baseline: 1.6630x; 1.0882x over previous
//
#include <hip/hip_runtime.h>
#include <stdint.h>

#define L48   48
#define NLOC  2304      // 48*48
#define C3CH  256
#define BATCH 4

typedef _Float16 half8 __attribute__((ext_vector_type(8)));
typedef float    floatx4 __attribute__((ext_vector_type(4)));
typedef unsigned short ushort8v __attribute__((ext_vector_type(8)));

union H16 { _Float16 f; unsigned short u; };

// ---------------- prep+ss fused: fp32 image -> K-major granule split-fp16 + per-pixel sum-of-squares ----------------
// grid 384: bid = im*192 + b*48 + y. im=0: refsr->A, im=1: lrsr->B.
// ss layout: [im][b][loc] (2 x 9216 floats, contiguous).
__global__ __launch_bounds__(256) void prep_ss_kernel(const float* __restrict__ img0,
                                                      const float* __restrict__ img1,
                                                      unsigned short* __restrict__ A_hi,
                                                      unsigned short* __restrict__ A_lo,
                                                      unsigned short* __restrict__ B_hi,
                                                      unsigned short* __restrict__ B_lo,
                                                      float* __restrict__ ss2)
{
    __shared__ unsigned short hi[256 * 48];
    __shared__ unsigned short lo[256 * 48];
    __shared__ float part[192];
    const float inv2048 = 1.0f / 2048.0f;

    int bid = blockIdx.x;
    int im  = bid / 192;
    int rem = bid - im * 192;
    int b   = rem / 48;
    int y   = rem - b * 48;
    int t = threadIdx.x;

    const float* ibase = (im ? img1 : img0) + (size_t)b * C3CH * NLOC + (size_t)y * L48;
    unsigned short* ohi = im ? B_hi : A_hi;
    unsigned short* olo = im ? B_lo : A_lo;

    for (int flat = t; flat < 256 * 48; flat += 256) {
        int c = flat / 48;
        int x = flat - c * 48;
        float v = ibase[(size_t)c * NLOC + x];
        H16 h, l;
        h.f = (_Float16)v;
        float rvv = (v - (float)h.f) * 2048.0f;
        l.f = (_Float16)rvv;
        hi[flat] = h.u;
        lo[flat] = l.u;
    }
    __syncthreads();

    if (t < 192) {
        int x = t >> 2, p = t & 3;
        float a = 0.f;
        #pragma unroll 8
        for (int c = p * 64; c < p * 64 + 64; ++c) {
            H16 h, l; h.u = hi[c * 48 + x]; l.u = lo[c * 48 + x];
            float vr = (float)h.f + (float)l.f * inv2048;
            a += vr * vr;
        }
        part[t] = a;
    }

    for (int flat = t; flat < 32 * 48; flat += 256) {
        int G = flat / 48;
        int x = flat - G * 48;
        ushort8v vh, vl;
        #pragma unroll
        for (int j = 0; j < 8; ++j) {
            vh[j] = hi[(G * 8 + j) * 48 + x];
            vl[j] = lo[(G * 8 + j) * 48 + x];
        }
        size_t o8 = ((size_t)(b * 32 + G) * NLOC + (size_t)y * 48 + x) * 8;
        *(ushort8v*)(ohi + o8) = vh;
        *(ushort8v*)(olo + o8) = vl;
    }
    __syncthreads();
    if (t < 48)
        ss2[(size_t)im * (BATCH * NLOC) + (size_t)b * NLOC + y * L48 + t] =
            part[t * 4] + part[t * 4 + 1] + part[t * 4 + 2] + part[t * 4 + 3];
}

// ---------------- norms: 3x3 stencil over both ss maps (nr_inv | nl_inv contiguous) ----------------
__global__ __launch_bounds__(256) void norm_from_ss2(const float* __restrict__ ss2,
                                                     float* __restrict__ inv2)
{
    int i = blockIdx.x * 256 + threadIdx.x;     // grid 72 -> 18432 exact
    int bb = i / NLOC, m = i - bb * NLOC;       // bb in [0,8)
    int y = m / L48, x = m - y * L48;
    const float* s = ss2 + (size_t)bb * NLOC;
    float a = 0.f;
    #pragma unroll
    for (int dy = -1; dy <= 1; ++dy) {
        int yy = y + dy;
        if ((unsigned)yy >= 48u) continue;
        #pragma unroll
        for (int dx = -1; dx <= 1; ++dx) {
            int xx = x + dx;
            if ((unsigned)xx >= 48u) continue;
            a += s[yy * L48 + xx];
        }
    }
    inv2[i] = 1.f / fmaxf(sqrtf(a), 1e-12f);
}

// ---------------- pass 1: pixel-correlation GEMM D = ref^T * lr (K=256), hi/lo split fp16 (unchanged) ----------------
__device__ __forceinline__ void stage_arr(const unsigned short* __restrict__ gbase,
                                          int loc0,
                                          unsigned short* lbase,
                                          int wv, int lane)
{
    #pragma unroll
    for (int j = 0; j < 2; ++j) {
        int bg = (j * 4 + wv) * 64;          // base granule in [0,512)
        int q  = bg >> 7;
        int r0 = bg & 127;
        const unsigned short* gp = gbase + ((size_t)q * NLOC + loc0 + r0 + lane) * 8;
        unsigned short* lp = lbase + (size_t)(bg + lane) * 8;
        __builtin_amdgcn_global_load_lds((const __attribute__((address_space(1))) void*)gp,
                                         (__attribute__((address_space(3))) void*)lp,
                                         16, 0, 0);
    }
}

__global__ __launch_bounds__(256, 2) void dgemm_mfma(const unsigned short* __restrict__ At_hi,
                                                     const unsigned short* __restrict__ At_lo,
                                                     const unsigned short* __restrict__ Bt_hi,
                                                     const unsigned short* __restrict__ Bt_lo,
                                                     int b,
                                                     float* __restrict__ D)
{
    __shared__ __align__(16) unsigned short lds[2 * 4 * 4096];

    const int tid = threadIdx.x;
    const int l0 = blockIdx.y * 128;   // ref rows
    const int m0 = blockIdx.x * 128;   // lr cols

    const int lane = tid & 63;
    const int wv = tid >> 6;
    const int wr = tid >> 7;
    const int wc = (tid >> 6) & 1;
    const int mrow = lane & 15;
    const int q = lane >> 4;

    floatx4 acc1[4][4];
    floatx4 acc2[4][4];
    #pragma unroll
    for (int i = 0; i < 4; ++i)
        #pragma unroll
        for (int j = 0; j < 4; ++j) { acc1[i][j] = (floatx4)0.f; acc2[i][j] = (floatx4)0.f; }

    auto issue = [&](int it, int sel) {
        int cc = it;
        size_t gb = (size_t)(b * 32 + cc * 4) * ((size_t)NLOC * 8);
        unsigned short* L = (unsigned short*)lds + sel * 16384;
        stage_arr(At_hi + gb, l0, L,         wv, lane);
        stage_arr(At_lo + gb, l0, L + 4096,  wv, lane);
        stage_arr(Bt_hi + gb, m0, L + 8192,  wv, lane);
        stage_arr(Bt_lo + gb, m0, L + 12288, wv, lane);
    };

    issue(0, 0);
    __syncthreads();

    for (int it = 0; it < 8; ++it) {
        const int sel = it & 1;
        if (it + 1 < 8) issue(it + 1, sel ^ 1);

        const _Float16* L  = (const _Float16*)((unsigned short*)lds + sel * 16384);
        const _Float16* Ah = L;
        const _Float16* Al = L + 4096;
        const _Float16* Bh = L + 8192;
        const _Float16* Bl = L + 12288;

        half8 ahf[4], alf[4];
        #pragma unroll
        for (int fi = 0; fi < 4; ++fi) {
            int g = q * 128 + wr * 64 + fi * 16 + mrow;
            ahf[fi] = *(const half8*)(Ah + g * 8);
            alf[fi] = *(const half8*)(Al + g * 8);
        }
        #pragma unroll
        for (int fj = 0; fj < 4; ++fj) {
            int g = q * 128 + wc * 64 + fj * 16 + mrow;
            half8 bhf = *(const half8*)(Bh + g * 8);
            half8 blf = *(const half8*)(Bl + g * 8);
            #pragma unroll
            for (int fi = 0; fi < 4; ++fi) {
                acc1[fi][fj] = __builtin_amdgcn_mfma_f32_16x16x32_f16(ahf[fi], bhf, acc1[fi][fj], 0, 0, 0);
                acc2[fi][fj] = __builtin_amdgcn_mfma_f32_16x16x32_f16(ahf[fi], blf, acc2[fi][fj], 0, 0, 0);
                acc2[fi][fj] = __builtin_amdgcn_mfma_f32_16x16x32_f16(alf[fi], bhf, acc2[fi][fj], 0, 0, 0);
            }
        }
        __syncthreads();
    }

    const float inv2048 = 1.0f / 2048.0f;
    #pragma unroll
    for (int fi = 0; fi < 4; ++fi) {
        int rowbase = l0 + wr * 64 + fi * 16 + (lane >> 4) * 4;
        #pragma unroll
        for (int r = 0; r < 4; ++r) {
            int row = rowbase + r;
            #pragma unroll
            for (int fj = 0; fj < 4; ++fj) {
                int col = m0 + wc * 64 + fj * 16 + mrow;
                D[(size_t)row * NLOC + col] = acc1[fi][fj][r] + acc2[fi][fj][r] * inv2048;
            }
        }
    }
}

// ---------------- pass 2: diagonal 3x3 stencil on D + row-normalize + argmax (unchanged) ----------------
#define LCH 4
__global__ __launch_bounds__(256) void stencil_argmax(const float* __restrict__ D,
                                                      const float* __restrict__ nr_inv,
                                                      int b,
                                                      unsigned long long* __restrict__ packed)
{
    __shared__ float S[3][2304];
    const int my  = blockIdx.x;
    const int ly0 = blockIdx.y * LCH;
    const int t   = threadIdx.x;

    float bestv[9];
    int   besti[9];
    #pragma unroll
    for (int k = 0; k < 9; ++k) { bestv[k] = -1e30f; besti[k] = 0; }

    for (int ly = ly0; ly < ly0 + LCH; ++ly) {
        #pragma unroll
        for (int dy = 0; dy < 3; ++dy) {
            int u = ly + dy - 1;
            int v = my + dy - 1;
            bool ok = ((unsigned)u < 48u) && ((unsigned)v < 48u);
            const float* dp = D + ((size_t)u * 48) * NLOC + (size_t)v * 48;
            for (int flat = t; flat < 2304; flat += 256) {
                int lxp = flat / 48, mxp = flat - lxp * 48;
                S[dy][flat] = ok ? dp[(size_t)lxp * NLOC + mxp] : 0.f;
            }
        }
        __syncthreads();

        #pragma unroll
        for (int k = 0; k < 9; ++k) {
            int p  = t + 256 * k;
            int lx = p / 48, mx = p - lx * 48;
            float s = 0.f;
            #pragma unroll
            for (int dy = 0; dy < 3; ++dy) {
                #pragma unroll
                for (int dx = 0; dx < 3; ++dx) {
                    int xl = lx + dx - 1;
                    int xm = mx + dx - 1;
                    bool ok = ((unsigned)xl < 48u) && ((unsigned)xm < 48u);
                    float v = S[dy][ok ? (xl * 48 + xm) : 0];
                    s += ok ? v : 0.f;
                }
            }
            float v = s * nr_inv[b * NLOC + ly * 48 + lx];
            if (v > bestv[k]) { bestv[k] = v; besti[k] = ly * 48 + lx; }
        }
        __syncthreads();
    }

    float* redv = &S[0][0];
    int*   redi = (int*)&S[1][0];
    #pragma unroll
    for (int k = 0; k < 9; ++k) {
        int p = t + 256 * k;
        redv[p] = bestv[k];
        redi[p] = besti[k];
    }
    __syncthreads();
    if (t < 48) {
        int mx = t;
        float best = -1e30f;
        int   bi   = 0x7FFFFFFF;
        for (int lx = 0; lx < 48; ++lx) {
            float v  = redv[lx * 48 + mx];
            int   i2 = redi[lx * 48 + mx];
            if (v > best || (v == best && i2 < bi)) { best = v; bi = i2; }
        }
        unsigned int sv = __float_as_uint(best);
        sv = (sv & 0x80000000u) ? ~sv : (sv | 0x80000000u);
        unsigned long long pk = ((unsigned long long)sv << 32)
                              | (unsigned long long)(0xFFFFFFFFu - (unsigned)bi);
        atomicMax(packed + b * NLOC + my * 48 + mx, pk);
    }
}

// ---------------- finalize: unpack S and argmax (unchanged) ----------------
__global__ __launch_bounds__(256) void finalize_kernel(const unsigned long long* __restrict__ packed,
                                                       const float* __restrict__ nl_inv,
                                                       float* __restrict__ S,
                                                       int* __restrict__ Rarg)
{
    int i = blockIdx.x * 256 + threadIdx.x;
    if (i >= BATCH * NLOC) return;
    unsigned long long p = packed[i];
    unsigned int sv   = (unsigned int)(p >> 32);
    unsigned int bits = (sv & 0x80000000u) ? (sv & 0x7FFFFFFFu) : ~sv;
    float val = __uint_as_float(bits);
    int   idx = (int)(0xFFFFFFFFu - (unsigned int)(p & 0xFFFFFFFFu));
    S[i]    = val * nl_inv[i];
    Rarg[i] = idx;
}

// ------------- transfer: fused gather + fold, S-wide vectorized, residue-aligned windows -------------
// Residue iteration: the <=3 consecutive windows in [xlo..xhi] hit each px%3 residue exactly once.
// At fixed (uu,tt), the 3 lanes xq in {px-1,px,px+1} share the same window px (same q), reading
// contiguous S-floats chunks of the same 3S-float run -> coalesced in ONE instruction.
template<int N> struct VecT;
template<> struct VecT<1> { using type = float; };
template<> struct VecT<2> { using type = float __attribute__((ext_vector_type(2))); };
template<> struct VecT<4> { using type = float __attribute__((ext_vector_type(4))); };

template<int C, int H, int S>
__device__ __forceinline__ void transfer_dev(const float* __restrict__ ref,
                                             const int* __restrict__ Rarg,
                                             float* __restrict__ out,
                                             int bid)
{
    using fvec = typename VecT<S>::type;
    int idx = bid * 256 + threadIdx.x;          // exactly B*C*H*48 threads
    int xq = idx % 48;
    int y  = (idx / 48) % H;
    int c  = (idx / (48 * H)) % C;
    int b  = idx / (48 * H * C);
    int x0 = xq * S;

    int u = xq + 1;
    int xlo = (u - 2 > 0) ? u - 2 : 0;
    int xhi = (u < 47) ? u : 47;
    int v = y / S + 1;
    int ylo = (v - 2 > 0) ? v - 2 : 0;
    int yhi = (v < 47) ? v : 47;

    int pxs[3], pys[3];
    bool okx[3], oky[3];
    int xr = xlo % 3, yr = ylo % 3;
    #pragma unroll
    for (int tt = 0; tt < 3; ++tt) {
        int px = xlo + ((tt - xr + 3) % 3);
        pxs[tt] = px; okx[tt] = (px <= xhi);
        int py = ylo + ((tt - yr + 3) % 3);
        pys[tt] = py; oky[tt] = (py <= yhi);
    }

    const float* rbase = ref + ((size_t)b * C + c) * H * H;
    const int*   abase = Rarg + b * NLOC;

    int qv[3][3];
    #pragma unroll
    for (int uu = 0; uu < 3; ++uu) {
        int py = pys[uu]; py = (py > 47) ? 47 : py;
        #pragma unroll
        for (int tt = 0; tt < 3; ++tt) {
            int px = pxs[tt]; px = (px > 47) ? 47 : px;
            qv[uu][tt] = abase[py * L48 + px];
        }
    }

    fvec acc = (fvec)(0.f);
    #pragma unroll
    for (int uu = 0; uu < 3; ++uu) {
        int py = pys[uu];
        bool yok = oky[uu];
        #pragma unroll
        for (int tt = 0; tt < 3; ++tt) {
            int px = pxs[tt];
            bool ok = yok && okx[tt];
            int q  = qv[uu][tt];
            int qy = q / L48, qx = q - qy * L48;
            int row = y  + S * (qy - py);
            int cb  = x0 + S * (qx - px);
            ok = ok && ((unsigned)row < (unsigned)H) && ((unsigned)cb < (unsigned)H);
            int off = ok ? (row * H + cb) : 0;
            fvec val = *(const fvec*)(rbase + off);
            acc += ok ? val : (fvec)(0.f);
        }
    }
    *(fvec*)(out + ((size_t)b * C + c) * H * H + (size_t)y * H + x0) = acc * (1.f / 9.f);
}

// one fat dispatch: T1 range first (longest), T2/T3 fill its tail
__global__ __launch_bounds__(256) void transfer_all(const float* __restrict__ ref1,
                                                    const float* __restrict__ ref2,
                                                    const float* __restrict__ ref3,
                                                    const int* __restrict__ Rarg,
                                                    float* __restrict__ T1,
                                                    float* __restrict__ T2,
                                                    float* __restrict__ T3)
{
    int bid = blockIdx.x;
    if (bid < 9216)       transfer_dev< 64, 192, 4>(ref1, Rarg, T1, bid);
    else if (bid < 18432) transfer_dev<128,  96, 2>(ref2, Rarg, T2, bid - 9216);
    else                  transfer_dev<256,  48, 1>(ref3, Rarg, T3, bid - 18432);
}

extern "C" void kernel_launch(void* const* d_in, const int* in_sizes, int n_in,
                              void* d_out, int out_size, void* d_ws, size_t ws_size,
                              hipStream_t stream)
{
    const float* lrsr  = (const float*)d_in[0];
    const float* refsr = (const float*)d_in[1];
    const float* ref1  = (const float*)d_in[2];
    const float* ref2  = (const float*)d_in[3];
    const float* ref3  = (const float*)d_in[4];

    float* S_out  = (float*)d_out;                   // 9216
    float* T3_out = S_out  + BATCH * NLOC;           // 2359296
    float* T2_out = T3_out + BATCH * 256 * 48 * 48;  // 4718592
    float* T1_out = T2_out + BATCH * 128 * 96 * 96;  // 9437184

    char* ws = (char*)d_ws;
    unsigned long long* packed = (unsigned long long*)ws;         // 73728 B
    float* nr_inv = (float*)(ws + 73728);                         // 36864 B  (nr|nl contiguous)
    float* nl_inv = (float*)(ws + 110592);                        // 36864 B
    int*   Rarg   = (int*)(ws + 147456);                          // 36864 B
    float* ss2    = (float*)(ws + 184320);                        // 73728 B (ss_ref | ss_lr)
    const size_t ASZ = (size_t)BATCH * NLOC * C3CH;               // 2359296 ushorts
    unsigned short* A_hi = (unsigned short*)(ws + 258048);
    unsigned short* A_lo = A_hi + ASZ;
    unsigned short* B_hi = A_lo + ASZ;
    unsigned short* B_lo = B_hi + ASZ;
    float* D = (float*)(ws + 258048 + 4 * ASZ * sizeof(unsigned short));  // 21.2 MB, one batch

    hipMemsetAsync(packed, 0, BATCH * NLOC * sizeof(unsigned long long), stream);

    prep_ss_kernel<<<dim3(384), 256, 0, stream>>>(refsr, lrsr, A_hi, A_lo, B_hi, B_lo, ss2);
    norm_from_ss2<<<dim3(72), 256, 0, stream>>>(ss2, nr_inv);   // writes nr_inv then nl_inv (contiguous)

    for (int b = 0; b < BATCH; ++b) {
        dgemm_mfma<<<dim3(18, 18), 256, 0, stream>>>(A_hi, A_lo, B_hi, B_lo, b, D);
        stencil_argmax<<<dim3(48, 48 / LCH), 256, 0, stream>>>(D, nr_inv, b, packed);
    }

    finalize_kernel<<<dim3(36), 256, 0, stream>>>(packed, nl_inv, S_out, Rarg);

    transfer_all<<<dim3(27648), 256, 0, stream>>>(ref1, ref2, ref3, Rarg, T1_out, T2_out, T3_out);
}

// Round 7
// 413.846 us; speedup vs baseline: 2.0930x; 1.2586x over previous
//
#include <hip/hip_runtime.h>
#include <stdint.h>

#define L48   48
#define NLOC  2304      // 48*48
#define C3CH  256
#define BATCH 4

typedef _Float16 half8 __attribute__((ext_vector_type(8)));
typedef float    floatx4 __attribute__((ext_vector_type(4)));
typedef unsigned short ushort8v __attribute__((ext_vector_type(8)));

union H16 { _Float16 f; unsigned short u; };

// ---------------- prep+ss fused (unchanged) ----------------
__global__ __launch_bounds__(256) void prep_ss_kernel(const float* __restrict__ img0,
                                                      const float* __restrict__ img1,
                                                      unsigned short* __restrict__ A_hi,
                                                      unsigned short* __restrict__ A_lo,
                                                      unsigned short* __restrict__ B_hi,
                                                      unsigned short* __restrict__ B_lo,
                                                      float* __restrict__ ss2)
{
    __shared__ unsigned short hi[256 * 48];
    __shared__ unsigned short lo[256 * 48];
    __shared__ float part[192];
    const float inv2048 = 1.0f / 2048.0f;

    int bid = blockIdx.x;
    int im  = bid / 192;
    int rem = bid - im * 192;
    int b   = rem / 48;
    int y   = rem - b * 48;
    int t = threadIdx.x;

    const float* ibase = (im ? img1 : img0) + (size_t)b * C3CH * NLOC + (size_t)y * L48;
    unsigned short* ohi = im ? B_hi : A_hi;
    unsigned short* olo = im ? B_lo : A_lo;

    for (int flat = t; flat < 256 * 48; flat += 256) {
        int c = flat / 48;
        int x = flat - c * 48;
        float v = ibase[(size_t)c * NLOC + x];
        H16 h, l;
        h.f = (_Float16)v;
        float rvv = (v - (float)h.f) * 2048.0f;
        l.f = (_Float16)rvv;
        hi[flat] = h.u;
        lo[flat] = l.u;
    }
    __syncthreads();

    if (t < 192) {
        int x = t >> 2, p = t & 3;
        float a = 0.f;
        #pragma unroll 8
        for (int c = p * 64; c < p * 64 + 64; ++c) {
            H16 h, l; h.u = hi[c * 48 + x]; l.u = lo[c * 48 + x];
            float vr = (float)h.f + (float)l.f * inv2048;
            a += vr * vr;
        }
        part[t] = a;
    }

    for (int flat = t; flat < 32 * 48; flat += 256) {
        int G = flat / 48;
        int x = flat - G * 48;
        ushort8v vh, vl;
        #pragma unroll
        for (int j = 0; j < 8; ++j) {
            vh[j] = hi[(G * 8 + j) * 48 + x];
            vl[j] = lo[(G * 8 + j) * 48 + x];
        }
        size_t o8 = ((size_t)(b * 32 + G) * NLOC + (size_t)y * 48 + x) * 8;
        *(ushort8v*)(ohi + o8) = vh;
        *(ushort8v*)(olo + o8) = vl;
    }
    __syncthreads();
    if (t < 48)
        ss2[(size_t)im * (BATCH * NLOC) + (size_t)b * NLOC + y * L48 + t] =
            part[t * 4] + part[t * 4 + 1] + part[t * 4 + 2] + part[t * 4 + 3];
}

// ---------------- norms: 3x3 stencil over both ss maps (unchanged) ----------------
__global__ __launch_bounds__(256) void norm_from_ss2(const float* __restrict__ ss2,
                                                     float* __restrict__ inv2)
{
    int i = blockIdx.x * 256 + threadIdx.x;     // grid 72 -> 18432 exact
    int bb = i / NLOC, m = i - bb * NLOC;
    int y = m / L48, x = m - y * L48;
    const float* s = ss2 + (size_t)bb * NLOC;
    float a = 0.f;
    #pragma unroll
    for (int dy = -1; dy <= 1; ++dy) {
        int yy = y + dy;
        if ((unsigned)yy >= 48u) continue;
        #pragma unroll
        for (int dx = -1; dx <= 1; ++dx) {
            int xx = x + dx;
            if ((unsigned)xx >= 48u) continue;
            a += s[yy * L48 + xx];
        }
    }
    inv2[i] = 1.f / fmaxf(sqrtf(a), 1e-12f);
}

// ---------------- pass 1: pixel-correlation GEMM, 2 batches per launch, XCD-grouped tiles ----------------
__device__ __forceinline__ void stage_arr(const unsigned short* __restrict__ gbase,
                                          int loc0,
                                          unsigned short* lbase,
                                          int wv, int lane)
{
    #pragma unroll
    for (int j = 0; j < 2; ++j) {
        int bg = (j * 4 + wv) * 64;          // base granule in [0,512)
        int q  = bg >> 7;
        int r0 = bg & 127;
        const unsigned short* gp = gbase + ((size_t)q * NLOC + loc0 + r0 + lane) * 8;
        unsigned short* lp = lbase + (size_t)(bg + lane) * 8;
        __builtin_amdgcn_global_load_lds((const __attribute__((address_space(1))) void*)gp,
                                         (__attribute__((address_space(3))) void*)lp,
                                         16, 0, 0);
    }
}

__global__ __launch_bounds__(256, 2) void dgemm_mfma(const unsigned short* __restrict__ At_hi,
                                                     const unsigned short* __restrict__ At_lo,
                                                     const unsigned short* __restrict__ Bt_hi,
                                                     const unsigned short* __restrict__ Bt_lo,
                                                     int b0,
                                                     float* __restrict__ D)
{
    __shared__ __align__(16) unsigned short lds[2 * 4 * 4096];

    // XCD-grouped work assignment: grid (18,18,2) = 648 = 81*8.
    // orig follows dispatch order (x fastest); each XCD gets 81 consecutive w,
    // decoded tx-fastest so blocks sharing an A-panel (same ty) are XCD-local.
    int orig = blockIdx.x + 18 * (blockIdx.y + 18 * blockIdx.z);
    int w    = (orig & 7) * 81 + (orig >> 3);
    int zz   = w / 324;
    int rem  = w - zz * 324;
    int ty   = rem / 18;
    int tx   = rem - ty * 18;

    const int tid = threadIdx.x;
    const int b  = b0 + zz;
    const int l0 = ty * 128;   // ref rows
    const int m0 = tx * 128;   // lr cols
    float* Dz = D + (size_t)zz * NLOC * NLOC;

    const int lane = tid & 63;
    const int wv = tid >> 6;
    const int wr = tid >> 7;
    const int wc = (tid >> 6) & 1;
    const int mrow = lane & 15;
    const int q = lane >> 4;

    floatx4 acc1[4][4];
    floatx4 acc2[4][4];
    #pragma unroll
    for (int i = 0; i < 4; ++i)
        #pragma unroll
        for (int j = 0; j < 4; ++j) { acc1[i][j] = (floatx4)0.f; acc2[i][j] = (floatx4)0.f; }

    auto issue = [&](int it, int sel) {
        int cc = it;
        size_t gb = (size_t)(b * 32 + cc * 4) * ((size_t)NLOC * 8);
        unsigned short* L = (unsigned short*)lds + sel * 16384;
        stage_arr(At_hi + gb, l0, L,         wv, lane);
        stage_arr(At_lo + gb, l0, L + 4096,  wv, lane);
        stage_arr(Bt_hi + gb, m0, L + 8192,  wv, lane);
        stage_arr(Bt_lo + gb, m0, L + 12288, wv, lane);
    };

    issue(0, 0);
    __syncthreads();

    for (int it = 0; it < 8; ++it) {
        const int sel = it & 1;
        if (it + 1 < 8) issue(it + 1, sel ^ 1);

        const _Float16* L  = (const _Float16*)((unsigned short*)lds + sel * 16384);
        const _Float16* Ah = L;
        const _Float16* Al = L + 4096;
        const _Float16* Bh = L + 8192;
        const _Float16* Bl = L + 12288;

        half8 ahf[4], alf[4];
        #pragma unroll
        for (int fi = 0; fi < 4; ++fi) {
            int g = q * 128 + wr * 64 + fi * 16 + mrow;
            ahf[fi] = *(const half8*)(Ah + g * 8);
            alf[fi] = *(const half8*)(Al + g * 8);
        }
        #pragma unroll
        for (int fj = 0; fj < 4; ++fj) {
            int g = q * 128 + wc * 64 + fj * 16 + mrow;
            half8 bhf = *(const half8*)(Bh + g * 8);
            half8 blf = *(const half8*)(Bl + g * 8);
            #pragma unroll
            for (int fi = 0; fi < 4; ++fi) {
                acc1[fi][fj] = __builtin_amdgcn_mfma_f32_16x16x32_f16(ahf[fi], bhf, acc1[fi][fj], 0, 0, 0);
                acc2[fi][fj] = __builtin_amdgcn_mfma_f32_16x16x32_f16(ahf[fi], blf, acc2[fi][fj], 0, 0, 0);
                acc2[fi][fj] = __builtin_amdgcn_mfma_f32_16x16x32_f16(alf[fi], bhf, acc2[fi][fj], 0, 0, 0);
            }
        }
        __syncthreads();
    }

    const float inv2048 = 1.0f / 2048.0f;
    #pragma unroll
    for (int fi = 0; fi < 4; ++fi) {
        int rowbase = l0 + wr * 64 + fi * 16 + (lane >> 4) * 4;
        #pragma unroll
        for (int r = 0; r < 4; ++r) {
            int row = rowbase + r;
            #pragma unroll
            for (int fj = 0; fj < 4; ++fj) {
                int col = m0 + wc * 64 + fj * 16 + mrow;
                Dz[(size_t)row * NLOC + col] = acc1[fi][fj][r] + acc2[fi][fj][r] * inv2048;
            }
        }
    }
}

// ---------------- pass 2: diagonal 3x3 stencil on D + argmax, 2 batches per launch, XCD-grouped ----------------
#define LCH 4
__global__ __launch_bounds__(256) void stencil_argmax(const float* __restrict__ D,
                                                      const float* __restrict__ nr_inv,
                                                      int b0,
                                                      unsigned long long* __restrict__ packed)
{
    __shared__ float S[3][2304];

    // grid (48,12,2) = 1152 = 144*8; blocks sharing my (D column band) are XCD-local.
    int orig = blockIdx.x + 48 * (blockIdx.y + 12 * blockIdx.z);
    int w    = (orig & 7) * 144 + (orig >> 3);
    int zz   = w / 576;
    int rem  = w - zz * 576;
    const int my  = rem / 12;
    const int ly0 = (rem - my * 12) * LCH;
    const int b   = b0 + zz;
    const float* Dz = D + (size_t)zz * NLOC * NLOC;
    const int t   = threadIdx.x;

    float bestv[9];
    int   besti[9];
    #pragma unroll
    for (int k = 0; k < 9; ++k) { bestv[k] = -1e30f; besti[k] = 0; }

    for (int ly = ly0; ly < ly0 + LCH; ++ly) {
        #pragma unroll
        for (int dy = 0; dy < 3; ++dy) {
            int u = ly + dy - 1;
            int v = my + dy - 1;
            bool ok = ((unsigned)u < 48u) && ((unsigned)v < 48u);
            const float* dp = Dz + ((size_t)u * 48) * NLOC + (size_t)v * 48;
            for (int flat = t; flat < 2304; flat += 256) {
                int lxp = flat / 48, mxp = flat - lxp * 48;
                S[dy][flat] = ok ? dp[(size_t)lxp * NLOC + mxp] : 0.f;
            }
        }
        __syncthreads();

        #pragma unroll
        for (int k = 0; k < 9; ++k) {
            int p  = t + 256 * k;
            int lx = p / 48, mx = p - lx * 48;
            float s = 0.f;
            #pragma unroll
            for (int dy = 0; dy < 3; ++dy) {
                #pragma unroll
                for (int dx = 0; dx < 3; ++dx) {
                    int xl = lx + dx - 1;
                    int xm = mx + dx - 1;
                    bool ok = ((unsigned)xl < 48u) && ((unsigned)xm < 48u);
                    float v = S[dy][ok ? (xl * 48 + xm) : 0];
                    s += ok ? v : 0.f;
                }
            }
            float v = s * nr_inv[b * NLOC + ly * 48 + lx];
            if (v > bestv[k]) { bestv[k] = v; besti[k] = ly * 48 + lx; }
        }
        __syncthreads();
    }

    float* redv = &S[0][0];
    int*   redi = (int*)&S[1][0];
    #pragma unroll
    for (int k = 0; k < 9; ++k) {
        int p = t + 256 * k;
        redv[p] = bestv[k];
        redi[p] = besti[k];
    }
    __syncthreads();
    if (t < 48) {
        int mx = t;
        float best = -1e30f;
        int   bi   = 0x7FFFFFFF;
        for (int lx = 0; lx < 48; ++lx) {
            float v  = redv[lx * 48 + mx];
            int   i2 = redi[lx * 48 + mx];
            if (v > best || (v == best && i2 < bi)) { best = v; bi = i2; }
        }
        unsigned int sv = __float_as_uint(best);
        sv = (sv & 0x80000000u) ? ~sv : (sv | 0x80000000u);
        unsigned long long pk = ((unsigned long long)sv << 32)
                              | (unsigned long long)(0xFFFFFFFFu - (unsigned)bi);
        atomicMax(packed + b * NLOC + my * 48 + mx, pk);
    }
}

// ---------------- finalize (unchanged) ----------------
__global__ __launch_bounds__(256) void finalize_kernel(const unsigned long long* __restrict__ packed,
                                                       const float* __restrict__ nl_inv,
                                                       float* __restrict__ S,
                                                       int* __restrict__ Rarg)
{
    int i = blockIdx.x * 256 + threadIdx.x;
    if (i >= BATCH * NLOC) return;
    unsigned long long p = packed[i];
    unsigned int sv   = (unsigned int)(p >> 32);
    unsigned int bits = (sv & 0x80000000u) ? (sv & 0x7FFFFFFFu) : ~sv;
    float val = __uint_as_float(bits);
    int   idx = (int)(0xFFFFFFFFu - (unsigned int)(p & 0xFFFFFFFFu));
    S[i]    = val * nl_inv[i];
    Rarg[i] = idx;
}

// ------------- transfer: residue-aligned gather+fold, XCD-grouped planes -------------
template<int N> struct VecT;
template<> struct VecT<1> { using type = float; };
template<> struct VecT<2> { using type = float __attribute__((ext_vector_type(2))); };
template<> struct VecT<4> { using type = float __attribute__((ext_vector_type(4))); };

template<int C, int H, int S>
__device__ __forceinline__ void transfer_dev(const float* __restrict__ ref,
                                             const int* __restrict__ Rarg,
                                             float* __restrict__ out,
                                             int bid)
{
    using fvec = typename VecT<S>::type;
    int idx = bid * 256 + threadIdx.x;
    int xq = idx % 48;
    int y  = (idx / 48) % H;
    int c  = (idx / (48 * H)) % C;
    int b  = idx / (48 * H * C);
    int x0 = xq * S;

    int u = xq + 1;
    int xlo = (u - 2 > 0) ? u - 2 : 0;
    int xhi = (u < 47) ? u : 47;
    int v = y / S + 1;
    int ylo = (v - 2 > 0) ? v - 2 : 0;
    int yhi = (v < 47) ? v : 47;

    int pxs[3], pys[3];
    bool okx[3], oky[3];
    int xr = xlo % 3, yr = ylo % 3;
    #pragma unroll
    for (int tt = 0; tt < 3; ++tt) {
        int px = xlo + ((tt - xr + 3) % 3);
        pxs[tt] = px; okx[tt] = (px <= xhi);
        int py = ylo + ((tt - yr + 3) % 3);
        pys[tt] = py; oky[tt] = (py <= yhi);
    }

    const float* rbase = ref + ((size_t)b * C + c) * H * H;
    const int*   abase = Rarg + b * NLOC;

    int qv[3][3];
    #pragma unroll
    for (int uu = 0; uu < 3; ++uu) {
        int py = pys[uu]; py = (py > 47) ? 47 : py;
        #pragma unroll
        for (int tt = 0; tt < 3; ++tt) {
            int px = pxs[tt]; px = (px > 47) ? 47 : px;
            qv[uu][tt] = abase[py * L48 + px];
        }
    }

    fvec acc = (fvec)(0.f);
    #pragma unroll
    for (int uu = 0; uu < 3; ++uu) {
        int py = pys[uu];
        bool yok = oky[uu];
        #pragma unroll
        for (int tt = 0; tt < 3; ++tt) {
            int px = pxs[tt];
            bool ok = yok && okx[tt];
            int q  = qv[uu][tt];
            int qy = q / L48, qx = q - qy * L48;
            int row = y  + S * (qy - py);
            int cb  = x0 + S * (qx - px);
            ok = ok && ((unsigned)row < (unsigned)H) && ((unsigned)cb < (unsigned)H);
            int off = ok ? (row * H + cb) : 0;
            fvec val = *(const fvec*)(rbase + off);
            acc += ok ? val : (fvec)(0.f);
        }
    }
    *(fvec*)(out + ((size_t)b * C + c) * H * H + (size_t)y * H + x0) = acc * (1.f / 9.f);
}

// one fat dispatch. XCD-grouped: each XCD owns w-chunk of 3456 blocks; all region/plane
// boundaries are multiples of the relevant blocks-per-plane (36/18/9), so no plane
// is split across XCDs -> each (b,c) ref plane is fetched into ONE L2, not eight.
__global__ __launch_bounds__(256) void transfer_all(const float* __restrict__ ref1,
                                                    const float* __restrict__ ref2,
                                                    const float* __restrict__ ref3,
                                                    const int* __restrict__ Rarg,
                                                    float* __restrict__ T1,
                                                    float* __restrict__ T2,
                                                    float* __restrict__ T3)
{
    int orig = blockIdx.x;                    // 27648 = 3456*8
    int w = (orig & 7) * 3456 + (orig >> 3);
    if (w < 9216)       transfer_dev< 64, 192, 4>(ref1, Rarg, T1, w);
    else if (w < 18432) transfer_dev<128,  96, 2>(ref2, Rarg, T2, w - 9216);
    else                transfer_dev<256,  48, 1>(ref3, Rarg, T3, w - 18432);
}

extern "C" void kernel_launch(void* const* d_in, const int* in_sizes, int n_in,
                              void* d_out, int out_size, void* d_ws, size_t ws_size,
                              hipStream_t stream)
{
    const float* lrsr  = (const float*)d_in[0];
    const float* refsr = (const float*)d_in[1];
    const float* ref1  = (const float*)d_in[2];
    const float* ref2  = (const float*)d_in[3];
    const float* ref3  = (const float*)d_in[4];

    float* S_out  = (float*)d_out;                   // 9216
    float* T3_out = S_out  + BATCH * NLOC;           // 2359296
    float* T2_out = T3_out + BATCH * 256 * 48 * 48;  // 4718592
    float* T1_out = T2_out + BATCH * 128 * 96 * 96;  // 9437184

    char* ws = (char*)d_ws;
    unsigned long long* packed = (unsigned long long*)ws;         // 73728 B
    float* nr_inv = (float*)(ws + 73728);                         // 36864 B  (nr|nl contiguous)
    float* nl_inv = (float*)(ws + 110592);                        // 36864 B
    int*   Rarg   = (int*)(ws + 147456);                          // 36864 B
    float* ss2    = (float*)(ws + 184320);                        // 73728 B
    const size_t ASZ = (size_t)BATCH * NLOC * C3CH;               // 2359296 ushorts
    unsigned short* A_hi = (unsigned short*)(ws + 258048);
    unsigned short* A_lo = A_hi + ASZ;
    unsigned short* B_hi = A_lo + ASZ;
    unsigned short* B_lo = B_hi + ASZ;

    // D scratch (2 batches, 42.5 MB) lives in d_out's T3|T2|T1 region (66 MB contiguous):
    // all stencil reads of D complete before transfer_all overwrites the region.
    float* D = T3_out;

    hipMemsetAsync(packed, 0, BATCH * NLOC * sizeof(unsigned long long), stream);

    prep_ss_kernel<<<dim3(384), 256, 0, stream>>>(refsr, lrsr, A_hi, A_lo, B_hi, B_lo, ss2);
    norm_from_ss2<<<dim3(72), 256, 0, stream>>>(ss2, nr_inv);

    for (int bp = 0; bp < 2; ++bp) {
        dgemm_mfma<<<dim3(18, 18, 2), 256, 0, stream>>>(A_hi, A_lo, B_hi, B_lo, bp * 2, D);
        stencil_argmax<<<dim3(48, 12, 2), 256, 0, stream>>>(D, nr_inv, bp * 2, packed);
    }

    finalize_kernel<<<dim3(36), 256, 0, stream>>>(packed, nl_inv, S_out, Rarg);

    transfer_all<<<dim3(27648), 256, 0, stream>>>(ref1, ref2, ref3, Rarg, T1_out, T2_out, T3_out);
}